// Round 3
// baseline (2298.242 us; speedup 1.0000x reference)
//
#include <hip/hip_runtime.h>
#include <hip/hip_bf16.h>
#include <cstdint>
#include <cstddef>

// MXAttention: B=4, S=1024, E=1024, H=16, D=64. All tensors fp32.
// MX quant: blocks of 32 along last/contraction dim,
// scale = 2^(floor(log2(amax))-8) clipped to E8M0 range, values rounded
// half-even onto the e4m3 grid (subnormals at e=-6, clip +-448).
//
// ws layout (floats):
//   [0      , 4M )  xq   (quantized input)  -- later reused as ctx / ctxq
//   [4M     , 5M )  Wq_q
//   [5M     , 6M )  Wk_q
//   [6M     , 7M )  Wv_q
//   [7M     , 8M )  Wo_q
//   [8M     ,12M )  Q
//   [12M    ,16M )  K
//   [16M    ,20M )  V
// total 20M floats = 80 MB.

#define S_LEN 1024
#define E_DIM 1024
#define NH    16
#define DH    64
#define BATCH 4
#define NROWS (BATCH * S_LEN)  // 4096

// ---------------- MX quant helpers ----------------

// Round v to the fp8-e4m3 grid (round-half-even), matching the reference:
//   e = max(floor(log2(|v|)), -6); step = 2^(e-3); q = rint(v/step)*step; clip 448.
__device__ __forceinline__ float qdq_e4m3(float v) {
  float a = __builtin_fabsf(v);
  if (a == 0.0f) return 0.0f;
  int e = (int)((__float_as_uint(a) >> 23) & 0xFFu) - 127;  // exact floor(log2(a)) for normals
  if (e < -6) e = -6;
  float stepinv = ldexpf(1.0f, 3 - e);   // exact power of two
  float step    = ldexpf(1.0f, e - 3);
  float q = rintf(v * stepinv) * step;   // v*2^k exact; rint = half-even
  q = fminf(fmaxf(q, -448.0f), 448.0f);
  return q;
}

// scale = 2^(clip(floor(log2(amax)) - 8, -127, 127)); 1.0 if amax == 0.
__device__ __forceinline__ void mx_scale(float amax, float& scale, float& inv) {
  if (amax > 0.0f) {
    int se = (int)((__float_as_uint(amax) >> 23) & 0xFFu) - 127 - 8;
    se = se < -127 ? -127 : (se > 127 ? 127 : se);
    scale = ldexpf(1.0f, se);
    inv   = ldexpf(1.0f, -se);
  } else {
    scale = 1.0f;
    inv   = 1.0f;
  }
}

__device__ __forceinline__ void qdq_block32(float* v) {
  float amax = 0.0f;
#pragma unroll
  for (int i = 0; i < 32; ++i) amax = fmaxf(amax, __builtin_fabsf(v[i]));
  float scale, inv;
  mx_scale(amax, scale, inv);
#pragma unroll
  for (int i = 0; i < 32; ++i) v[i] = qdq_e4m3(v[i] * inv) * scale;
}

// ---------------- quant kernel ----------------
// One thread per 32-element block; fp32 in, fp32 out (in==out allowed).

__global__ __launch_bounds__(256)
void mxq_kernel(const float* __restrict__ in, float* __restrict__ out, int nblk) {
  int b = blockIdx.x * 256 + threadIdx.x;
  if (b >= nblk) return;
  const float4* p = (const float4*)(in + (size_t)b * 32);
  float v[32];
#pragma unroll
  for (int g = 0; g < 8; ++g) {
    float4 t = p[g];
    v[g * 4 + 0] = t.x; v[g * 4 + 1] = t.y; v[g * 4 + 2] = t.z; v[g * 4 + 3] = t.w;
  }
  qdq_block32(v);
  float4* q = (float4*)(out + (size_t)b * 32);
#pragma unroll
  for (int g = 0; g < 8; ++g)
    q[g] = make_float4(v[g * 4 + 0], v[g * 4 + 1], v[g * 4 + 2], v[g * 4 + 3]);
}

// ---------------- fp32 NT GEMM: C[m,n] = sum_k A[m,k]*B[n,k] + bias[n] ----------------
// 128x128 tile, BK=8, 256 threads, 8x8 per thread.

__global__ __launch_bounds__(256)
void gemm_nt(const float* __restrict__ A, const float* __restrict__ Bw,
             const float* __restrict__ bias, float* __restrict__ Cout,
             int M, int N, int K) {
  constexpr int BM = 128, BN = 128, BK = 8;
  __shared__ float sA[BK][BM + 1];
  __shared__ float sB[BK][BN + 1];
  const int tid = threadIdx.x;
  const int bm = blockIdx.y * BM;
  const int bn = blockIdx.x * BN;
  const int lr = tid >> 1;         // 0..127
  const int lk = (tid & 1) * 4;    // 0 or 4
  const int tx = (tid & 15) * 8;
  const int ty = (tid >> 4) * 8;

  float acc[8][8];
#pragma unroll
  for (int i = 0; i < 8; ++i)
#pragma unroll
    for (int j = 0; j < 8; ++j) acc[i][j] = 0.0f;

  for (int k0 = 0; k0 < K; k0 += BK) {
    float4 a4 = *(const float4*)(A  + (size_t)(bm + lr) * K + k0 + lk);
    float4 b4 = *(const float4*)(Bw + (size_t)(bn + lr) * K + k0 + lk);
    __syncthreads();
    sA[lk + 0][lr] = a4.x; sA[lk + 1][lr] = a4.y; sA[lk + 2][lr] = a4.z; sA[lk + 3][lr] = a4.w;
    sB[lk + 0][lr] = b4.x; sB[lk + 1][lr] = b4.y; sB[lk + 2][lr] = b4.z; sB[lk + 3][lr] = b4.w;
    __syncthreads();
#pragma unroll
    for (int k = 0; k < BK; ++k) {
      float ar[8], br[8];
#pragma unroll
      for (int i = 0; i < 8; ++i) ar[i] = sA[k][ty + i];
#pragma unroll
      for (int j = 0; j < 8; ++j) br[j] = sB[k][tx + j];
#pragma unroll
      for (int i = 0; i < 8; ++i)
#pragma unroll
        for (int j = 0; j < 8; ++j) acc[i][j] += ar[i] * br[j];
    }
  }

  float bv[8];
#pragma unroll
  for (int j = 0; j < 8; ++j) bv[j] = bias[bn + tx + j];
#pragma unroll
  for (int i = 0; i < 8; ++i) {
    float* o = Cout + (size_t)(bm + ty + i) * N + bn + tx;
#pragma unroll
    for (int j = 0; j < 8; ++j) o[j] = acc[i][j] + bv[j];
  }
}

// ---------------- attention ----------------
// grid (16, B*H): one WG per (b,h, 64 q-rows). kv tiles of 128.
// thread t: q-row r = t>>2, kv 32-block j = t&3 (aligned with MX quant blocks).
// Online softmax over e4m3-quantized scores; ctx partials reduced across the quad.
// LDS: K+V tiles = 64 KB (q rows read straight from global, L1/L2-cached).

__global__ __launch_bounds__(256, 2)
void attn_kernel(const float* __restrict__ Qm, const float* __restrict__ Km,
                 const float* __restrict__ Vm, float* __restrict__ ctx) {
  constexpr int QT = 64, KT = 128;
  __shared__ float Ks[KT][DH];
  __shared__ float Vs[KT][DH];
  const int tid = threadIdx.x;
  const int qt = blockIdx.x;   // 0..15
  const int bh = blockIdx.y;   // 0..63
  const int b = bh >> 4, h = bh & 15;
  const int q0 = qt * QT;
  const size_t base = ((size_t)b * S_LEN) * E_DIM + (size_t)h * DH;

  const int r = tid >> 2;
  const int j = tid & 3;
  float qreg[DH];
  {
    const float* qp = Qm + base + (size_t)(q0 + r) * E_DIM;
#pragma unroll
    for (int f = 0; f < 16; ++f)
      *(float4*)&qreg[f * 4] = *(const float4*)(qp + f * 4);
  }

  float ctxa[DH];
#pragma unroll
  for (int d = 0; d < DH; ++d) ctxa[d] = 0.0f;
  float m = -3.0e38f, l = 0.0f;

#pragma unroll 1
  for (int kt = 0; kt < S_LEN / KT; ++kt) {
    __syncthreads();
    for (int i = tid; i < KT * (DH / 4); i += 256) {
      int c = i >> 4, f = i & 15;
      size_t g = base + (size_t)(kt * KT + c) * E_DIM + f * 4;
      *(float4*)&Ks[c][f * 4] = *(const float4*)(Km + g);
      *(float4*)&Vs[c][f * 4] = *(const float4*)(Vm + g);
    }
    __syncthreads();

    float s[32];
    float amax = 0.0f;
#pragma unroll
    for (int ci = 0; ci < 32; ++ci) {
      const float* kp = &Ks[j * 32 + ci][0];
      float dot = 0.0f;
#pragma unroll
      for (int f = 0; f < 16; ++f) {
        float4 k4 = *(const float4*)(kp + f * 4);
        dot += qreg[f * 4 + 0] * k4.x + qreg[f * 4 + 1] * k4.y +
               qreg[f * 4 + 2] * k4.z + qreg[f * 4 + 3] * k4.w;
      }
      dot *= 0.125f;  // 1/sqrt(64)
      s[ci] = dot;
      amax = fmaxf(amax, __builtin_fabsf(dot));
    }
    float scale, inv;
    mx_scale(amax, scale, inv);
    float mt = -3.0e38f;
#pragma unroll
    for (int ci = 0; ci < 32; ++ci) {
      float q = qdq_e4m3(s[ci] * inv) * scale;
      s[ci] = q;
      mt = fmaxf(mt, q);
    }
    mt = fmaxf(mt, __shfl_xor(mt, 1, 64));
    mt = fmaxf(mt, __shfl_xor(mt, 2, 64));
    float mnew = fmaxf(m, mt);
    float alpha = __expf(m - mnew);  // first tile: exp(-huge) = 0
    l *= alpha;
#pragma unroll
    for (int d = 0; d < DH; ++d) ctxa[d] *= alpha;
#pragma unroll
    for (int ci = 0; ci < 32; ++ci) {
      float p = __expf(s[ci] - mnew);
      l += p;
      const float* vp = &Vs[j * 32 + ci][0];
#pragma unroll
      for (int f = 0; f < 16; ++f) {
        float4 v4 = *(const float4*)(vp + f * 4);
        ctxa[f * 4 + 0] += p * v4.x; ctxa[f * 4 + 1] += p * v4.y;
        ctxa[f * 4 + 2] += p * v4.z; ctxa[f * 4 + 3] += p * v4.w;
      }
    }
    m = mnew;
  }

  l += __shfl_xor(l, 1, 64);
  l += __shfl_xor(l, 2, 64);
  float invl = 1.0f / l;
#pragma unroll
  for (int d = 0; d < DH; ++d) {
    ctxa[d] += __shfl_xor(ctxa[d], 1, 64);
    ctxa[d] += __shfl_xor(ctxa[d], 2, 64);
  }
  // thread j writes d-range [j*16, j*16+16)
#pragma unroll
  for (int jj = 0; jj < 4; ++jj) {
    if (j == jj) {
      float* op = ctx + base + (size_t)(q0 + r) * E_DIM + jj * 16;
#pragma unroll
      for (int f = 0; f < 4; ++f) {
        float4 o4 = make_float4(ctxa[jj * 16 + f * 4 + 0] * invl,
                                ctxa[jj * 16 + f * 4 + 1] * invl,
                                ctxa[jj * 16 + f * 4 + 2] * invl,
                                ctxa[jj * 16 + f * 4 + 3] * invl);
        *(float4*)(op + f * 4) = o4;
      }
    }
  }
}

// ---------------- launch ----------------

extern "C" void kernel_launch(void* const* d_in, const int* in_sizes, int n_in,
                              void* d_out, int out_size, void* d_ws, size_t ws_size,
                              hipStream_t stream) {
  (void)in_sizes; (void)n_in; (void)out_size; (void)ws_size;
  const float* x  = (const float*)d_in[0];
  const float* Wq = (const float*)d_in[1];
  const float* bq = (const float*)d_in[2];
  const float* Wk = (const float*)d_in[3];
  const float* bk = (const float*)d_in[4];
  const float* Wv = (const float*)d_in[5];
  const float* bv = (const float*)d_in[6];
  const float* Wo = (const float*)d_in[7];
  const float* bo = (const float*)d_in[8];

  float* ws = (float*)d_ws;
  const size_t M1 = (size_t)1 << 20;
  float* XQ  = ws;             // 4M floats; later reused as ctx/ctxq
  float* WQQ = ws + 4 * M1;
  float* WKQ = ws + 5 * M1;
  float* WVQ = ws + 6 * M1;
  float* WOQ = ws + 7 * M1;
  float* Qb  = ws + 8 * M1;
  float* Kb  = ws + 12 * M1;
  float* Vb  = ws + 16 * M1;
  float* CTX = XQ;

  const int nblk_x = NROWS * E_DIM / 32;  // 131072
  const int nblk_w = E_DIM * E_DIM / 32;  // 32768

  mxq_kernel<<<nblk_x / 256, 256, 0, stream>>>(x,  XQ,  nblk_x);
  mxq_kernel<<<nblk_w / 256, 256, 0, stream>>>(Wq, WQQ, nblk_w);
  mxq_kernel<<<nblk_w / 256, 256, 0, stream>>>(Wk, WKQ, nblk_w);
  mxq_kernel<<<nblk_w / 256, 256, 0, stream>>>(Wv, WVQ, nblk_w);
  mxq_kernel<<<nblk_w / 256, 256, 0, stream>>>(Wo, WOQ, nblk_w);

  dim3 ggrid(E_DIM / 128, NROWS / 128);  // (8, 32)
  gemm_nt<<<ggrid, 256, 0, stream>>>(XQ, WQQ, bq, Qb, NROWS, E_DIM, E_DIM);
  gemm_nt<<<ggrid, 256, 0, stream>>>(XQ, WKQ, bk, Kb, NROWS, E_DIM, E_DIM);
  gemm_nt<<<ggrid, 256, 0, stream>>>(XQ, WVQ, bv, Vb, NROWS, E_DIM, E_DIM);

  dim3 agrid(S_LEN / 64, BATCH * NH);  // (16, 64)
  attn_kernel<<<agrid, 256, 0, stream>>>(Qb, Kb, Vb, CTX);

  mxq_kernel<<<nblk_x / 256, 256, 0, stream>>>(CTX, CTX, nblk_x);

  gemm_nt<<<ggrid, 256, 0, stream>>>(CTX, WOQ, bo, (float*)d_out, NROWS, E_DIM, E_DIM);
}

// Round 4
// 822.070 us; speedup vs baseline: 2.7957x; 2.7957x over previous
//
#include <hip/hip_runtime.h>
#include <hip/hip_bf16.h>
#include <cstdint>
#include <cstddef>

// MXAttention: B=4, S=1024, E=1024, H=16, D=64. fp32 in/out.
// MX quant: blocks of 32 along last/contraction dim, scale=2^(floor(log2(amax))-8),
// e4m3 round-half-even grid (subnormals at e=-6, clip +-448).
//
// Quantized tensors are e4m3-values x power-of-two scale => <=4-bit significands
// => EXACTLY representable in bf16. GEMMs run bf16-MFMA with fp32 accumulation:
// bit-equivalent to fp32 GEMM modulo accumulation order.
//
// ws layout (bytes):
//   [ 0MB,  8MB)  XQb   bf16 quantized input; later reused as CTXQb
//   [ 8MB, 10MB)  WQb   bf16
//   [10MB, 12MB)  WKb
//   [12MB, 14MB)  WVb
//   [14MB, 16MB)  WOb
//   [16MB, 32MB)  Qb    fp32
//   [32MB, 48MB)  Kb
//   [48MB, 64MB)  Vb
//   [64MB, 80MB)  CTX   fp32
// total 80 MB.

#define S_LEN 1024
#define E_DIM 1024
#define NH    16
#define DH    64
#define BATCH 4
#define NROWS (BATCH * S_LEN)  // 4096

typedef short          bf16x8  __attribute__((ext_vector_type(8)));
typedef float          f32x4   __attribute__((ext_vector_type(4)));
typedef unsigned short u16x8   __attribute__((ext_vector_type(8)));

// ---------------- MX quant helpers ----------------

__device__ __forceinline__ float qdq_e4m3(float v) {
  float a = __builtin_fabsf(v);
  if (a == 0.0f) return 0.0f;
  int e = (int)((__float_as_uint(a) >> 23) & 0xFFu) - 127;  // exact floor(log2) for normals
  if (e < -6) e = -6;
  float stepinv = ldexpf(1.0f, 3 - e);
  float step    = ldexpf(1.0f, e - 3);
  float q = rintf(v * stepinv) * step;   // half-even
  q = fminf(fmaxf(q, -448.0f), 448.0f);
  return q;
}

__device__ __forceinline__ void mx_scale(float amax, float& scale, float& inv) {
  if (amax > 0.0f) {
    int se = (int)((__float_as_uint(amax) >> 23) & 0xFFu) - 127 - 8;
    se = se < -127 ? -127 : (se > 127 ? 127 : se);
    scale = ldexpf(1.0f, se);
    inv   = ldexpf(1.0f, -se);
  } else {
    scale = 1.0f;
    inv   = 1.0f;
  }
}

// ---------------- quant kernel: fp32 in -> bf16 out (exact) ----------------
// One thread per 32-element MX block.

__global__ __launch_bounds__(256)
void mxq_kernel(const float* __restrict__ in, unsigned short* __restrict__ out, int nblk) {
  int b = blockIdx.x * 256 + threadIdx.x;
  if (b >= nblk) return;
  const float4* p = (const float4*)(in + (size_t)b * 32);
  float v[32];
#pragma unroll
  for (int g = 0; g < 8; ++g) {
    float4 t = p[g];
    v[g * 4 + 0] = t.x; v[g * 4 + 1] = t.y; v[g * 4 + 2] = t.z; v[g * 4 + 3] = t.w;
  }
  float amax = 0.0f;
#pragma unroll
  for (int i = 0; i < 32; ++i) amax = fmaxf(amax, __builtin_fabsf(v[i]));
  float scale, inv;
  mx_scale(amax, scale, inv);
  u16x8* q = (u16x8*)(out + (size_t)b * 32);
#pragma unroll
  for (int g = 0; g < 4; ++g) {
    u16x8 o;
#pragma unroll
    for (int e = 0; e < 8; ++e) {
      float qv = qdq_e4m3(v[g * 8 + e] * inv) * scale;
      o[e] = (unsigned short)(__float_as_uint(qv) >> 16);  // exact: <=4-bit significand
    }
    q[g] = o;
  }
}

// ---------------- bf16 MFMA NT GEMM: C[m,n] = sum_k A[m,k]*B[n,k] + bias[n] --------
// 128x128 tile, BK=64, 256 threads (4 waves, each 64x64 = 4x4 MFMA 16x16x32 tiles).
// Staging via global_load_lds width=16; k-groups XOR-swizzled on the global side so
// fragment ds_read_b128 lands max 2-way (free).
// LDS layout: s[row][g] (row stride 64 bf16 = 128B) holds global k-group g ^ (row&7).

__global__ __launch_bounds__(256)
void gemm_mfma(const unsigned short* __restrict__ A, const unsigned short* __restrict__ Bw,
               const float* __restrict__ bias, float* __restrict__ C,
               int M, int N, int K) {
  __shared__ unsigned short sA[128 * 64];
  __shared__ unsigned short sB[128 * 64];
  const int tid = threadIdx.x;
  const int w = tid >> 6, ln = tid & 63;
  const int bm = blockIdx.y * 128, bn = blockIdx.x * 128;
  const int wm = (w >> 1) * 64, wn = (w & 1) * 64;

  f32x4 acc[4][4];
  f32x4 zero = {0.0f, 0.0f, 0.0f, 0.0f};
#pragma unroll
  for (int i = 0; i < 4; ++i)
#pragma unroll
    for (int j = 0; j < 4; ++j) acc[i][j] = zero;

  const int srow = ln >> 3;             // 0..7 within the 8-row group one instr stages
  const int gsw  = (ln & 7) ^ srow;     // swizzled global k-group for this lane

  for (int k0 = 0; k0 < K; k0 += 64) {
    __syncthreads();
#pragma unroll
    for (int q = 0; q < 4; ++q) {
      int row = w * 32 + q * 8 + srow;
      const unsigned short* ga = A  + (size_t)(bm + row) * K + k0 + gsw * 8;
      const unsigned short* gb = Bw + (size_t)(bn + row) * K + k0 + gsw * 8;
      __builtin_amdgcn_global_load_lds(
          (const __attribute__((address_space(1))) unsigned int*)ga,
          (__attribute__((address_space(3))) unsigned int*)(sA + (w * 32 + q * 8) * 64),
          16, 0, 0);
      __builtin_amdgcn_global_load_lds(
          (const __attribute__((address_space(1))) unsigned int*)gb,
          (__attribute__((address_space(3))) unsigned int*)(sB + (w * 32 + q * 8) * 64),
          16, 0, 0);
    }
    __syncthreads();

#pragma unroll
    for (int ks = 0; ks < 2; ++ks) {
      bf16x8 af[4], bf[4];
      const int gq = ks * 4 + (ln >> 4);  // needed k-group 0..7
#pragma unroll
      for (int t = 0; t < 4; ++t) {
        int m = wm + t * 16 + (ln & 15);
        af[t] = *(const bf16x8*)(sA + m * 64 + ((gq ^ (m & 7)) * 8));
        int n = wn + t * 16 + (ln & 15);
        bf[t] = *(const bf16x8*)(sB + n * 64 + ((gq ^ (n & 7)) * 8));
      }
#pragma unroll
      for (int ti = 0; ti < 4; ++ti)
#pragma unroll
        for (int tj = 0; tj < 4; ++tj)
          acc[ti][tj] = __builtin_amdgcn_mfma_f32_16x16x32_bf16(af[ti], bf[tj], acc[ti][tj], 0, 0, 0);
    }
  }

  // epilogue: C/D layout col=lane&15, row=(lane>>4)*4+reg
  const int quad = ln >> 4, col = ln & 15;
#pragma unroll
  for (int ti = 0; ti < 4; ++ti) {
#pragma unroll
    for (int tj = 0; tj < 4; ++tj) {
      int n = bn + wn + tj * 16 + col;
      float bv = bias[n];
#pragma unroll
      for (int i = 0; i < 4; ++i) {
        int m = bm + wm + ti * 16 + quad * 4 + i;
        C[(size_t)m * N + n] = acc[ti][tj][i] + bv;
      }
    }
  }
}

// ---------------- attention ----------------
// grid (16, B*H): one WG per (b,h, 64 q-rows). kv tiles of 64.
// thread t: q-row r = t>>2, quad member j = t&3 handling kv rows 4*ci+j (ci=0..15).
// Rows padded to 68 floats: simultaneous quad reads hit disjoint bank windows.
// Per-32-block score amax: split 8 vals/thread x 4 threads -> quad shfl-reduce.

__global__ __launch_bounds__(256, 2)
void attn_kernel(const float* __restrict__ Qm, const float* __restrict__ Km,
                 const float* __restrict__ Vm, float* __restrict__ ctx) {
  constexpr int QT = 64, KT = 64, PAD = DH + 4;
  __shared__ float Ks[KT][PAD];
  __shared__ float Vs[KT][PAD];
  const int tid = threadIdx.x;
  const int qt = blockIdx.x;   // 0..15
  const int bh = blockIdx.y;   // 0..63
  const int b = bh >> 4, h = bh & 15;
  const int q0 = qt * QT;
  const size_t base = ((size_t)b * S_LEN) * E_DIM + (size_t)h * DH;

  const int r = tid >> 2;
  const int j = tid & 3;
  float qreg[DH];
  {
    const float* qp = Qm + base + (size_t)(q0 + r) * E_DIM;
#pragma unroll
    for (int f = 0; f < 16; ++f)
      *(float4*)&qreg[f * 4] = *(const float4*)(qp + f * 4);
  }

  float ctxa[DH];
#pragma unroll
  for (int d = 0; d < DH; ++d) ctxa[d] = 0.0f;
  float m = -3.0e38f, l = 0.0f;

#pragma unroll 1
  for (int kt = 0; kt < S_LEN / KT; ++kt) {
    __syncthreads();
    for (int i = tid; i < KT * (DH / 4); i += 256) {
      int c = i >> 4, f = i & 15;
      size_t g = base + (size_t)(kt * KT + c) * E_DIM + f * 4;
      *(float4*)&Ks[c][f * 4] = *(const float4*)(Km + g);
      *(float4*)&Vs[c][f * 4] = *(const float4*)(Vm + g);
    }
    __syncthreads();

    float s[16];
    float am0 = 0.0f, am1 = 0.0f;
#pragma unroll
    for (int ci = 0; ci < 16; ++ci) {
      const float* kp = &Ks[4 * ci + j][0];
      float dot = 0.0f;
#pragma unroll
      for (int f = 0; f < 16; ++f) {
        float4 k4 = *(const float4*)(kp + f * 4);
        dot += qreg[f * 4 + 0] * k4.x + qreg[f * 4 + 1] * k4.y +
               qreg[f * 4 + 2] * k4.z + qreg[f * 4 + 3] * k4.w;
      }
      dot *= 0.125f;  // 1/sqrt(64)
      s[ci] = dot;
      float ad = __builtin_fabsf(dot);
      if (ci < 8) am0 = fmaxf(am0, ad); else am1 = fmaxf(am1, ad);
    }
    // quad-reduce the two block amaxes (kv blocks [0,32) and [32,64) of this tile)
    am0 = fmaxf(am0, __shfl_xor(am0, 1, 64));
    am0 = fmaxf(am0, __shfl_xor(am0, 2, 64));
    am1 = fmaxf(am1, __shfl_xor(am1, 1, 64));
    am1 = fmaxf(am1, __shfl_xor(am1, 2, 64));
    float sc0, iv0, sc1, iv1;
    mx_scale(am0, sc0, iv0);
    mx_scale(am1, sc1, iv1);

    float mt = -3.0e38f;
#pragma unroll
    for (int ci = 0; ci < 16; ++ci) {
      float sc = (ci < 8) ? sc0 : sc1;
      float iv = (ci < 8) ? iv0 : iv1;
      float q = qdq_e4m3(s[ci] * iv) * sc;
      s[ci] = q;
      mt = fmaxf(mt, q);
    }
    mt = fmaxf(mt, __shfl_xor(mt, 1, 64));
    mt = fmaxf(mt, __shfl_xor(mt, 2, 64));
    float mnew = fmaxf(m, mt);
    float alpha = __expf(m - mnew);  // first tile: exp(-huge) = 0
    l *= alpha;
#pragma unroll
    for (int d = 0; d < DH; ++d) ctxa[d] *= alpha;
#pragma unroll
    for (int ci = 0; ci < 16; ++ci) {
      float p = __expf(s[ci] - mnew);
      l += p;
      const float* vp = &Vs[4 * ci + j][0];
#pragma unroll
      for (int f = 0; f < 16; ++f) {
        float4 v4 = *(const float4*)(vp + f * 4);
        ctxa[f * 4 + 0] += p * v4.x; ctxa[f * 4 + 1] += p * v4.y;
        ctxa[f * 4 + 2] += p * v4.z; ctxa[f * 4 + 3] += p * v4.w;
      }
    }
    m = mnew;
  }

  l += __shfl_xor(l, 1, 64);
  l += __shfl_xor(l, 2, 64);
  float invl = 1.0f / l;
#pragma unroll
  for (int d = 0; d < DH; ++d) {
    ctxa[d] += __shfl_xor(ctxa[d], 1, 64);
    ctxa[d] += __shfl_xor(ctxa[d], 2, 64);
  }
#pragma unroll
  for (int jj = 0; jj < 4; ++jj) {
    if (j == jj) {
      float* op = ctx + base + (size_t)(q0 + r) * E_DIM + jj * 16;
#pragma unroll
      for (int f = 0; f < 4; ++f) {
        float4 o4 = make_float4(ctxa[jj * 16 + f * 4 + 0] * invl,
                                ctxa[jj * 16 + f * 4 + 1] * invl,
                                ctxa[jj * 16 + f * 4 + 2] * invl,
                                ctxa[jj * 16 + f * 4 + 3] * invl);
        *(float4*)(op + f * 4) = o4;
      }
    }
  }
}

// ---------------- launch ----------------

extern "C" void kernel_launch(void* const* d_in, const int* in_sizes, int n_in,
                              void* d_out, int out_size, void* d_ws, size_t ws_size,
                              hipStream_t stream) {
  (void)in_sizes; (void)n_in; (void)out_size; (void)ws_size;
  const float* x  = (const float*)d_in[0];
  const float* Wq = (const float*)d_in[1];
  const float* bq = (const float*)d_in[2];
  const float* Wk = (const float*)d_in[3];
  const float* bk = (const float*)d_in[4];
  const float* Wv = (const float*)d_in[5];
  const float* bv = (const float*)d_in[6];
  const float* Wo = (const float*)d_in[7];
  const float* bo = (const float*)d_in[8];

  char* wsb = (char*)d_ws;
  const size_t MB = (size_t)1 << 20;
  unsigned short* XQb   = (unsigned short*)(wsb + 0);
  unsigned short* WQb   = (unsigned short*)(wsb + 8 * MB);
  unsigned short* WKb   = (unsigned short*)(wsb + 10 * MB);
  unsigned short* WVb   = (unsigned short*)(wsb + 12 * MB);
  unsigned short* WOb   = (unsigned short*)(wsb + 14 * MB);
  float*          Qb    = (float*)(wsb + 16 * MB);
  float*          Kb    = (float*)(wsb + 32 * MB);
  float*          Vb    = (float*)(wsb + 48 * MB);
  float*          CTX   = (float*)(wsb + 64 * MB);
  unsigned short* CTXQb = XQb;  // reuse: XQ dead after V projection

  const int nblk_x = NROWS * E_DIM / 32;  // 131072
  const int nblk_w = E_DIM * E_DIM / 32;  // 32768

  mxq_kernel<<<nblk_x / 256, 256, 0, stream>>>(x,  XQb, nblk_x);
  mxq_kernel<<<nblk_w / 256, 256, 0, stream>>>(Wq, WQb, nblk_w);
  mxq_kernel<<<nblk_w / 256, 256, 0, stream>>>(Wk, WKb, nblk_w);
  mxq_kernel<<<nblk_w / 256, 256, 0, stream>>>(Wv, WVb, nblk_w);
  mxq_kernel<<<nblk_w / 256, 256, 0, stream>>>(Wo, WOb, nblk_w);

  dim3 ggrid(E_DIM / 128, NROWS / 128);  // (8, 32)
  gemm_mfma<<<ggrid, 256, 0, stream>>>(XQb, WQb, bq, Qb, NROWS, E_DIM, E_DIM);
  gemm_mfma<<<ggrid, 256, 0, stream>>>(XQb, WKb, bk, Kb, NROWS, E_DIM, E_DIM);
  gemm_mfma<<<ggrid, 256, 0, stream>>>(XQb, WVb, bv, Vb, NROWS, E_DIM, E_DIM);

  dim3 agrid(S_LEN / 64, BATCH * NH);  // (16, 64)
  attn_kernel<<<agrid, 256, 0, stream>>>(Qb, Kb, Vb, CTX);

  mxq_kernel<<<nblk_x / 256, 256, 0, stream>>>(CTX, CTXQb, nblk_x);

  gemm_mfma<<<ggrid, 256, 0, stream>>>(CTXQb, WOb, bo, (float*)d_out, NROWS, E_DIM, E_DIM);
}

// Round 5
// 365.602 us; speedup vs baseline: 6.2862x; 2.2485x over previous
//
#include <hip/hip_runtime.h>
#include <hip/hip_bf16.h>
#include <cstdint>
#include <cstddef>

// MXAttention: B=4, S=1024, E=1024, H=16, D=64. fp32 in/out.
// MX quant: blocks of 32 along last/contraction dim, scale=2^(floor(log2(amax))-8),
// e4m3 round-half-even grid (subnormals at e=-6, clip +-448).
//
// GEMMs: quantized operands are e4m3 x pow2 => exactly bf16 => bf16 MFMA, fp32 acc.
// Attention: fp32 Q,K,P,V split into bf16 hi+lo; products via 3 cross-term MFMAs
// (error ~2^-16, far below e4m3 boundary noise). V staged transposed (Vt[b,h,d,s])
// by the V-projection GEMM epilogue. ctx MX-quant fused into attention epilogue.
//
// ws layout (bytes):
//   [ 0MB,  8MB)  XQb   bf16 quantized input; later reused as CTXQb
//   [ 8MB, 10MB)  WQb   [10,12) WKb  [12,14) WVb  [14,16) WOb
//   [16MB, 32MB)  Qb    fp32
//   [32MB, 48MB)  Kb    fp32
//   [48MB, 64MB)  VtG   fp32 transposed V: [b][h][d][s]

#define S_LEN 1024
#define E_DIM 1024
#define NH    16
#define DH    64
#define BATCH 4
#define NROWS (BATCH * S_LEN)  // 4096

typedef short          bf16x8  __attribute__((ext_vector_type(8)));
typedef float          f32x4   __attribute__((ext_vector_type(4)));
typedef unsigned short u16x8   __attribute__((ext_vector_type(8)));

// ---------------- MX quant helpers ----------------

__device__ __forceinline__ float qdq_e4m3(float v) {
  float a = __builtin_fabsf(v);
  if (a == 0.0f) return 0.0f;
  int e = (int)((__float_as_uint(a) >> 23) & 0xFFu) - 127;  // exact floor(log2) for normals
  if (e < -6) e = -6;
  float stepinv = ldexpf(1.0f, 3 - e);
  float step    = ldexpf(1.0f, e - 3);
  float q = rintf(v * stepinv) * step;   // half-even
  q = fminf(fmaxf(q, -448.0f), 448.0f);
  return q;
}

__device__ __forceinline__ void mx_scale(float amax, float& scale, float& inv) {
  if (amax > 0.0f) {
    int se = (int)((__float_as_uint(amax) >> 23) & 0xFFu) - 127 - 8;
    se = se < -127 ? -127 : (se > 127 ? 127 : se);
    scale = ldexpf(1.0f, se);
    inv   = ldexpf(1.0f, -se);
  } else {
    scale = 1.0f;
    inv   = 1.0f;
  }
}

__device__ __forceinline__ unsigned short f32_to_bf16_rne(float f) {
  unsigned u = __float_as_uint(f);
  unsigned r = 0x7FFFu + ((u >> 16) & 1u);
  return (unsigned short)((u + r) >> 16);
}

// split 8 contiguous fp32 (scaled by pre) into bf16 hi/lo, write 16B each to LDS
__device__ __forceinline__ void split8(const float* __restrict__ g,
                                       short* __restrict__ hidst,
                                       short* __restrict__ lodst, float pre) {
  float4 a = *(const float4*)g, c = *(const float4*)(g + 4);
  float v[8] = {a.x, a.y, a.z, a.w, c.x, c.y, c.z, c.w};
  u16x8 hi, lo;
#pragma unroll
  for (int e = 0; e < 8; ++e) {
    float f = v[e] * pre;
    unsigned short h = f32_to_bf16_rne(f);
    float hf = __uint_as_float((unsigned)h << 16);
    lo[e] = f32_to_bf16_rne(f - hf);   // exact residual (Sterbenz), then rne
    hi[e] = h;
  }
  *(u16x8*)hidst = hi;
  *(u16x8*)lodst = lo;
}

// ---------------- quant kernel: fp32 in -> bf16 out (exact) ----------------

__global__ __launch_bounds__(256)
void mxq_kernel(const float* __restrict__ in, unsigned short* __restrict__ out, int nblk) {
  int b = blockIdx.x * 256 + threadIdx.x;
  if (b >= nblk) return;
  const float4* p = (const float4*)(in + (size_t)b * 32);
  float v[32];
#pragma unroll
  for (int g = 0; g < 8; ++g) {
    float4 t = p[g];
    v[g * 4 + 0] = t.x; v[g * 4 + 1] = t.y; v[g * 4 + 2] = t.z; v[g * 4 + 3] = t.w;
  }
  float amax = 0.0f;
#pragma unroll
  for (int i = 0; i < 32; ++i) amax = fmaxf(amax, __builtin_fabsf(v[i]));
  float scale, inv;
  mx_scale(amax, scale, inv);
  u16x8* q = (u16x8*)(out + (size_t)b * 32);
#pragma unroll
  for (int g = 0; g < 4; ++g) {
    u16x8 o;
#pragma unroll
    for (int e = 0; e < 8; ++e) {
      float qv = qdq_e4m3(v[g * 8 + e] * inv) * scale;
      o[e] = (unsigned short)(__float_as_uint(qv) >> 16);  // exact: <=4-bit significand
    }
    q[g] = o;
  }
}

// ---------------- bf16 MFMA NT GEMM ----------------
// C[m,n] = sum_k A[m,k]*B[n,k] + bias[n]. 128x128 tile, BK=64, 4 waves.
// VT=true: write transposed per-head (Vt[b][h][d][s]) instead of C[m][n].

template <bool VT>
__global__ __launch_bounds__(256)
void gemm_mfma(const unsigned short* __restrict__ A, const unsigned short* __restrict__ Bw,
               const float* __restrict__ bias, float* __restrict__ C,
               int M, int N, int K) {
  __shared__ unsigned short sA[128 * 64];
  __shared__ unsigned short sB[128 * 64];
  const int tid = threadIdx.x;
  const int w = tid >> 6, ln = tid & 63;
  const int bm = blockIdx.y * 128, bn = blockIdx.x * 128;
  const int wm = (w >> 1) * 64, wn = (w & 1) * 64;

  f32x4 acc[4][4];
  f32x4 zero = {0.0f, 0.0f, 0.0f, 0.0f};
#pragma unroll
  for (int i = 0; i < 4; ++i)
#pragma unroll
    for (int j = 0; j < 4; ++j) acc[i][j] = zero;

  const int srow = ln >> 3;
  const int gsw  = (ln & 7) ^ srow;

  for (int k0 = 0; k0 < K; k0 += 64) {
    __syncthreads();
#pragma unroll
    for (int q = 0; q < 4; ++q) {
      int row = w * 32 + q * 8 + srow;
      const unsigned short* ga = A  + (size_t)(bm + row) * K + k0 + gsw * 8;
      const unsigned short* gb = Bw + (size_t)(bn + row) * K + k0 + gsw * 8;
      __builtin_amdgcn_global_load_lds(
          (const __attribute__((address_space(1))) unsigned int*)ga,
          (__attribute__((address_space(3))) unsigned int*)(sA + (w * 32 + q * 8) * 64),
          16, 0, 0);
      __builtin_amdgcn_global_load_lds(
          (const __attribute__((address_space(1))) unsigned int*)gb,
          (__attribute__((address_space(3))) unsigned int*)(sB + (w * 32 + q * 8) * 64),
          16, 0, 0);
    }
    __syncthreads();

#pragma unroll
    for (int ks = 0; ks < 2; ++ks) {
      bf16x8 af[4], bf[4];
      const int gq = ks * 4 + (ln >> 4);
#pragma unroll
      for (int t = 0; t < 4; ++t) {
        int m = wm + t * 16 + (ln & 15);
        af[t] = *(const bf16x8*)(sA + m * 64 + ((gq ^ (m & 7)) * 8));
        int n = wn + t * 16 + (ln & 15);
        bf[t] = *(const bf16x8*)(sB + n * 64 + ((gq ^ (n & 7)) * 8));
      }
#pragma unroll
      for (int ti = 0; ti < 4; ++ti)
#pragma unroll
        for (int tj = 0; tj < 4; ++tj)
          acc[ti][tj] = __builtin_amdgcn_mfma_f32_16x16x32_bf16(af[ti], bf[tj], acc[ti][tj], 0, 0, 0);
    }
  }

  const int quad = ln >> 4, col = ln & 15;
#pragma unroll
  for (int ti = 0; ti < 4; ++ti) {
#pragma unroll
    for (int tj = 0; tj < 4; ++tj) {
      int n = bn + wn + tj * 16 + col;
      float bv = bias[n];
      if (VT) {
        // rows m0..m0+3 are consecutive s within one batch; n = h*64+d
        int m0 = bm + wm + ti * 16 + quad * 4;
        float4 o4 = make_float4(acc[ti][tj][0] + bv, acc[ti][tj][1] + bv,
                                acc[ti][tj][2] + bv, acc[ti][tj][3] + bv);
        size_t idx = ((size_t)((m0 >> 10) * 1024 + n)) * 1024 + (m0 & 1023);
        *(float4*)(C + idx) = o4;
      } else {
#pragma unroll
        for (int i = 0; i < 4; ++i) {
          int m = bm + wm + ti * 16 + quad * 4 + i;
          C[(size_t)m * N + n] = acc[ti][tj][i] + bv;
        }
      }
    }
  }
}

// ---------------- MFMA flash attention with fused score+ctx MX quant ----------
// grid (16, 64): WG = (qt, b*16+h), 64 q-rows, kv tiles of 64, 4 waves x 16 q-rows.
// LDS rows padded to 72 bf16 (144 B) -> fragment reads spread banks evenly.
// P (per-wave private, 16x68 u32) overlaps the K region behind a barrier.

__global__ __launch_bounds__(256)
void attn_kernel(const float* __restrict__ Qm, const float* __restrict__ Km,
                 const float* __restrict__ Vt, unsigned short* __restrict__ ctxq) {
  const int tid = threadIdx.x;
  const int qt = blockIdx.x, bh = blockIdx.y;
  const int b = bh >> 4, h = bh & 15;
  const int w = tid >> 6, ln = tid & 63, quad = ln >> 4, col = ln & 15;
  const int sr = tid >> 2, sc = tid & 3;

  __shared__ __align__(16) char smem[55296];
  short* Qhi = (short*)smem;                    // 64*72*2 = 9216 B each
  short* Qlo = (short*)(smem + 9216);
  short* Khi = (short*)(smem + 18432);
  short* Klo = (short*)(smem + 27648);
  short* Vhi = (short*)(smem + 36864);
  short* Vlo = (short*)(smem + 46080);
  unsigned int* Pw = (unsigned int*)(smem + 18432) + w * 1088;  // overlaps K region

  // stage Q once (pre-scaled by 1/sqrt(D) = 0.125, exact pow2)
  {
    const float* g = Qm + (size_t)(b * 1024 + qt * 64 + sr) * 1024 + h * 64 + sc * 16;
    split8(g,     Qhi + sr * 72 + sc * 16,     Qlo + sr * 72 + sc * 16,     0.125f);
    split8(g + 8, Qhi + sr * 72 + sc * 16 + 8, Qlo + sr * 72 + sc * 16 + 8, 0.125f);
  }
  __syncthreads();

  bf16x8 qh[2], ql[2];
#pragma unroll
  for (int ks = 0; ks < 2; ++ks) {
    qh[ks] = *(const bf16x8*)(Qhi + (w * 16 + col) * 72 + ks * 32 + quad * 8);
    ql[ks] = *(const bf16x8*)(Qlo + (w * 16 + col) * 72 + ks * 32 + quad * 8);
  }

  f32x4 o[4];
  f32x4 zero = {0.0f, 0.0f, 0.0f, 0.0f};
#pragma unroll
  for (int t = 0; t < 4; ++t) o[t] = zero;
  float m_[4], l_[4];
#pragma unroll
  for (int i = 0; i < 4; ++i) { m_[i] = -3.0e38f; l_[i] = 0.0f; }

#pragma unroll 1
  for (int kt = 0; kt < 16; ++kt) {
    __syncthreads();  // prior tile's P/Vt reads complete before restaging
    {
      const float* gk = Km + (size_t)(b * 1024 + kt * 64 + sr) * 1024 + h * 64 + sc * 16;
      split8(gk,     Khi + sr * 72 + sc * 16,     Klo + sr * 72 + sc * 16,     1.0f);
      split8(gk + 8, Khi + sr * 72 + sc * 16 + 8, Klo + sr * 72 + sc * 16 + 8, 1.0f);
      const float* gv = Vt + (size_t)(b * 1024 + h * 64 + sr) * 1024 + kt * 64 + sc * 16;
      split8(gv,     Vhi + sr * 72 + sc * 16,     Vlo + sr * 72 + sc * 16,     1.0f);
      split8(gv + 8, Vhi + sr * 72 + sc * 16 + 8, Vlo + sr * 72 + sc * 16 + 8, 1.0f);
    }
    __syncthreads();  // staging visible

    // S = (Qhi+Qlo)·(Khi+Klo)^T, 3 cross terms (lo·lo dropped, ~2^-16)
    f32x4 s[4];
#pragma unroll
    for (int t = 0; t < 4; ++t) s[t] = zero;
#pragma unroll
    for (int t = 0; t < 4; ++t) {
#pragma unroll
      for (int ks = 0; ks < 2; ++ks) {
        bf16x8 kh = *(const bf16x8*)(Khi + (t * 16 + col) * 72 + ks * 32 + quad * 8);
        bf16x8 kl = *(const bf16x8*)(Klo + (t * 16 + col) * 72 + ks * 32 + quad * 8);
        s[t] = __builtin_amdgcn_mfma_f32_16x16x32_bf16(ql[ks], kh, s[t], 0, 0, 0);
        s[t] = __builtin_amdgcn_mfma_f32_16x16x32_bf16(qh[ks], kl, s[t], 0, 0, 0);
        s[t] = __builtin_amdgcn_mfma_f32_16x16x32_bf16(qh[ks], kh, s[t], 0, 0, 0);
      }
    }

    // MX quantize scores: blocks of 32 kv = frag pairs (0,1) and (2,3)
    float am0[4], am1[4];
#pragma unroll
    for (int i = 0; i < 4; ++i) {
      am0[i] = fmaxf(__builtin_fabsf(s[0][i]), __builtin_fabsf(s[1][i]));
      am1[i] = fmaxf(__builtin_fabsf(s[2][i]), __builtin_fabsf(s[3][i]));
    }
#pragma unroll
    for (int msk = 1; msk <= 8; msk <<= 1)
#pragma unroll
      for (int i = 0; i < 4; ++i) {
        am0[i] = fmaxf(am0[i], __shfl_xor(am0[i], msk, 64));
        am1[i] = fmaxf(am1[i], __shfl_xor(am1[i], msk, 64));
      }
    float mt[4];
#pragma unroll
    for (int i = 0; i < 4; ++i) {
      float sc0, iv0, sc1, iv1;
      mx_scale(am0[i], sc0, iv0);
      mx_scale(am1[i], sc1, iv1);
      float q0 = qdq_e4m3(s[0][i] * iv0) * sc0;
      float q1 = qdq_e4m3(s[1][i] * iv0) * sc0;
      float q2 = qdq_e4m3(s[2][i] * iv1) * sc1;
      float q3 = qdq_e4m3(s[3][i] * iv1) * sc1;
      s[0][i] = q0; s[1][i] = q1; s[2][i] = q2; s[3][i] = q3;
      mt[i] = fmaxf(fmaxf(q0, q1), fmaxf(q2, q3));
    }
#pragma unroll
    for (int msk = 1; msk <= 8; msk <<= 1)
#pragma unroll
      for (int i = 0; i < 4; ++i) mt[i] = fmaxf(mt[i], __shfl_xor(mt[i], msk, 64));

    // online softmax
#pragma unroll
    for (int i = 0; i < 4; ++i) {
      float mnew  = fmaxf(m_[i], mt[i]);
      float alpha = __expf(m_[i] - mnew);
      m_[i] = mnew;
      l_[i] *= alpha;
#pragma unroll
      for (int t = 0; t < 4; ++t) o[t][i] *= alpha;
#pragma unroll
      for (int t = 0; t < 4; ++t) {
        float p = __expf(s[t][i] - mnew);
        s[t][i] = p;
        l_[i] += p;
      }
    }

    __syncthreads();  // all K fragment reads done before P overwrites K region

    // P: C-layout -> LDS (hi/lo packed u32) -> A-layout fragments
#pragma unroll
    for (int t = 0; t < 4; ++t)
#pragma unroll
      for (int i = 0; i < 4; ++i) {
        float p = s[t][i];
        unsigned short ph = f32_to_bf16_rne(p);
        float pf = __uint_as_float((unsigned)ph << 16);
        unsigned short pl = f32_to_bf16_rne(p - pf);
        Pw[(quad * 4 + i) * 68 + t * 16 + col] = ((unsigned)ph << 16) | pl;
      }
    bf16x8 pah[2], pal[2];
#pragma unroll
    for (int ks = 0; ks < 2; ++ks) {
      const unsigned int* pr = Pw + col * 68 + ks * 32 + quad * 8;
      uint4 u0 = *(const uint4*)pr;
      uint4 u1 = *(const uint4*)(pr + 4);
      unsigned int uu[8] = {u0.x, u0.y, u0.z, u0.w, u1.x, u1.y, u1.z, u1.w};
      bf16x8 hh, llv;
#pragma unroll
      for (int e = 0; e < 8; ++e) {
        hh[e]  = (short)(uu[e] >> 16);
        llv[e] = (short)(uu[e] & 0xffffu);
      }
      pah[ks] = hh; pal[ks] = llv;
    }

    // O += (Phi+Plo)·(Vhi+Vlo), 3 cross terms
#pragma unroll
    for (int nt = 0; nt < 4; ++nt) {
#pragma unroll
      for (int ks = 0; ks < 2; ++ks) {
        bf16x8 vh = *(const bf16x8*)(Vhi + (nt * 16 + col) * 72 + ks * 32 + quad * 8);
        bf16x8 vl = *(const bf16x8*)(Vlo + (nt * 16 + col) * 72 + ks * 32 + quad * 8);
        o[nt] = __builtin_amdgcn_mfma_f32_16x16x32_bf16(pal[ks], vh, o[nt], 0, 0, 0);
        o[nt] = __builtin_amdgcn_mfma_f32_16x16x32_bf16(pah[ks], vl, o[nt], 0, 0, 0);
        o[nt] = __builtin_amdgcn_mfma_f32_16x16x32_bf16(pah[ks], vh, o[nt], 0, 0, 0);
      }
    }
  }

  // normalize + fused ctx MX quant (blocks of 32 along E = frag pairs) -> bf16
#pragma unroll
  for (int msk = 1; msk <= 8; msk <<= 1)
#pragma unroll
    for (int i = 0; i < 4; ++i) l_[i] += __shfl_xor(l_[i], msk, 64);
  float cam0[4], cam1[4];
#pragma unroll
  for (int i = 0; i < 4; ++i) {
    float invl = 1.0f / l_[i];
#pragma unroll
    for (int t = 0; t < 4; ++t) o[t][i] *= invl;
    cam0[i] = fmaxf(__builtin_fabsf(o[0][i]), __builtin_fabsf(o[1][i]));
    cam1[i] = fmaxf(__builtin_fabsf(o[2][i]), __builtin_fabsf(o[3][i]));
  }
#pragma unroll
  for (int msk = 1; msk <= 8; msk <<= 1)
#pragma unroll
    for (int i = 0; i < 4; ++i) {
      cam0[i] = fmaxf(cam0[i], __shfl_xor(cam0[i], msk, 64));
      cam1[i] = fmaxf(cam1[i], __shfl_xor(cam1[i], msk, 64));
    }
#pragma unroll
  for (int i = 0; i < 4; ++i) {
    float sc0, iv0, sc1, iv1;
    mx_scale(cam0[i], sc0, iv0);
    mx_scale(cam1[i], sc1, iv1);
    int rowg = b * 1024 + qt * 64 + w * 16 + quad * 4 + i;
#pragma unroll
    for (int t = 0; t < 4; ++t) {
      float scq = (t < 2) ? sc0 : sc1;
      float ivq = (t < 2) ? iv0 : iv1;
      float q = qdq_e4m3(o[t][i] * ivq) * scq;
      ctxq[(size_t)rowg * 1024 + h * 64 + t * 16 + col] =
          (unsigned short)(__float_as_uint(q) >> 16);  // exact bf16
    }
  }
}

// ---------------- launch ----------------

extern "C" void kernel_launch(void* const* d_in, const int* in_sizes, int n_in,
                              void* d_out, int out_size, void* d_ws, size_t ws_size,
                              hipStream_t stream) {
  (void)in_sizes; (void)n_in; (void)out_size; (void)ws_size;
  const float* x  = (const float*)d_in[0];
  const float* Wq = (const float*)d_in[1];
  const float* bq = (const float*)d_in[2];
  const float* Wk = (const float*)d_in[3];
  const float* bk = (const float*)d_in[4];
  const float* Wv = (const float*)d_in[5];
  const float* bv = (const float*)d_in[6];
  const float* Wo = (const float*)d_in[7];
  const float* bo = (const float*)d_in[8];

  char* wsb = (char*)d_ws;
  const size_t MB = (size_t)1 << 20;
  unsigned short* XQb   = (unsigned short*)(wsb + 0);
  unsigned short* WQb   = (unsigned short*)(wsb + 8 * MB);
  unsigned short* WKb   = (unsigned short*)(wsb + 10 * MB);
  unsigned short* WVb   = (unsigned short*)(wsb + 12 * MB);
  unsigned short* WOb   = (unsigned short*)(wsb + 14 * MB);
  float*          Qb    = (float*)(wsb + 16 * MB);
  float*          Kb    = (float*)(wsb + 32 * MB);
  float*          VtG   = (float*)(wsb + 48 * MB);
  unsigned short* CTXQb = XQb;  // reuse: XQ dead after V projection

  const int nblk_x = NROWS * E_DIM / 32;  // 131072
  const int nblk_w = E_DIM * E_DIM / 32;  // 32768

  mxq_kernel<<<nblk_x / 256, 256, 0, stream>>>(x,  XQb, nblk_x);
  mxq_kernel<<<nblk_w / 256, 256, 0, stream>>>(Wq, WQb, nblk_w);
  mxq_kernel<<<nblk_w / 256, 256, 0, stream>>>(Wk, WKb, nblk_w);
  mxq_kernel<<<nblk_w / 256, 256, 0, stream>>>(Wv, WVb, nblk_w);
  mxq_kernel<<<nblk_w / 256, 256, 0, stream>>>(Wo, WOb, nblk_w);

  dim3 ggrid(E_DIM / 128, NROWS / 128);  // (8, 32)
  gemm_mfma<false><<<ggrid, 256, 0, stream>>>(XQb, WQb, bq, Qb,  NROWS, E_DIM, E_DIM);
  gemm_mfma<false><<<ggrid, 256, 0, stream>>>(XQb, WKb, bk, Kb,  NROWS, E_DIM, E_DIM);
  gemm_mfma<true ><<<ggrid, 256, 0, stream>>>(XQb, WVb, bv, VtG, NROWS, E_DIM, E_DIM);

  dim3 agrid(S_LEN / 64, BATCH * NH);  // (16, 64)
  attn_kernel<<<agrid, 256, 0, stream>>>(Qb, Kb, VtG, CTXQb);

  gemm_mfma<false><<<ggrid, 256, 0, stream>>>(CTXQb, WOb, bo, (float*)d_out, NROWS, E_DIM, E_DIM);
}

// Round 6
// 323.876 us; speedup vs baseline: 7.0961x; 1.1288x over previous
//
#include <hip/hip_runtime.h>
#include <hip/hip_bf16.h>
#include <cstdint>
#include <cstddef>

// MXAttention: B=4, S=1024, E=1024, H=16, D=64. fp32 in/out.
// MX quant: blocks of 32 along last/contraction dim, scale=2^(floor(log2(amax))-8),
// e4m3 round-half-even grid (subnormals at e=-6, clip +-448).
//
// GEMMs: quantized operands are e4m3 x pow2 => exactly bf16 => bf16 MFMA, fp32 acc.
// Q/K/V GEMM epilogues emit the fp32 result pre-split into bf16 hi+lo planes
// (v = hi + lo + eps, eps ~ 2^-17 rel); attention computes QK^T and PV via 3
// cross-term MFMAs (lo*lo dropped). V planes are stored transposed (Vt[b,h,d,s]).
// Attention stages K/V hi/lo via global_load_lds (no VALU), Q fragments straight
// from global. Score + ctx MX quant fused in-kernel.
//
// ws layout (bytes):
//   [ 0, 8)MB  XQb  bf16 quantized input; later reused as CTXQb
//   [ 8,16)MB  WQb/WKb/WVb/WOb (2 MB each)
//   [16,24) Qhi [24,32) Qlo   [32,40) Khi [40,48) Klo   [48,56) Vthi [56,64) Vtlo

#define S_LEN 1024
#define E_DIM 1024
#define NH    16
#define DH    64
#define BATCH 4
#define NROWS (BATCH * S_LEN)  // 4096

typedef short          bf16x8  __attribute__((ext_vector_type(8)));
typedef float          f32x4   __attribute__((ext_vector_type(4)));
typedef unsigned short u16x8   __attribute__((ext_vector_type(8)));
typedef unsigned short u16x4   __attribute__((ext_vector_type(4)));

// ---------------- MX quant helpers ----------------

__device__ __forceinline__ float qdq_e4m3(float v) {
  float a = __builtin_fabsf(v);
  if (a == 0.0f) return 0.0f;
  int e = (int)((__float_as_uint(a) >> 23) & 0xFFu) - 127;  // exact floor(log2) for normals
  if (e < -6) e = -6;
  float stepinv = ldexpf(1.0f, 3 - e);
  float step    = ldexpf(1.0f, e - 3);
  float q = rintf(v * stepinv) * step;   // half-even
  q = fminf(fmaxf(q, -448.0f), 448.0f);
  return q;
}

__device__ __forceinline__ void mx_scale(float amax, float& scale, float& inv) {
  if (amax > 0.0f) {
    int se = (int)((__float_as_uint(amax) >> 23) & 0xFFu) - 127 - 8;
    se = se < -127 ? -127 : (se > 127 ? 127 : se);
    scale = ldexpf(1.0f, se);
    inv   = ldexpf(1.0f, -se);
  } else {
    scale = 1.0f;
    inv   = 1.0f;
  }
}

__device__ __forceinline__ unsigned short f32_to_bf16_rne(float f) {
  unsigned u = __float_as_uint(f);
  unsigned r = 0x7FFFu + ((u >> 16) & 1u);
  return (unsigned short)((u + r) >> 16);
}

// ---------------- quant kernels: fp32 in -> bf16 out (exact) ----------------

__device__ __forceinline__ void mxq_body(const float* __restrict__ in,
                                         unsigned short* __restrict__ out, int b) {
  const float4* p = (const float4*)(in + (size_t)b * 32);
  float v[32];
#pragma unroll
  for (int g = 0; g < 8; ++g) {
    float4 t = p[g];
    v[g * 4 + 0] = t.x; v[g * 4 + 1] = t.y; v[g * 4 + 2] = t.z; v[g * 4 + 3] = t.w;
  }
  float amax = 0.0f;
#pragma unroll
  for (int i = 0; i < 32; ++i) amax = fmaxf(amax, __builtin_fabsf(v[i]));
  float scale, inv;
  mx_scale(amax, scale, inv);
  u16x8* q = (u16x8*)(out + (size_t)b * 32);
#pragma unroll
  for (int g = 0; g < 4; ++g) {
    u16x8 o;
#pragma unroll
    for (int e = 0; e < 8; ++e) {
      float qv = qdq_e4m3(v[g * 8 + e] * inv) * scale;
      o[e] = (unsigned short)(__float_as_uint(qv) >> 16);  // exact: <=4-bit significand
    }
    q[g] = o;
  }
}

__global__ __launch_bounds__(256)
void mxq_kernel(const float* __restrict__ in, unsigned short* __restrict__ out, int nblk) {
  int b = blockIdx.x * 256 + threadIdx.x;
  if (b < nblk) mxq_body(in, out, b);
}

__global__ __launch_bounds__(256)
void mxq4_kernel(const float* __restrict__ w0, const float* __restrict__ w1,
                 const float* __restrict__ w2, const float* __restrict__ w3,
                 unsigned short* __restrict__ o0, unsigned short* __restrict__ o1,
                 unsigned short* __restrict__ o2, unsigned short* __restrict__ o3,
                 int nblk) {
  int b = blockIdx.x * 256 + threadIdx.x;
  if (b >= nblk) return;
  const float* in = (blockIdx.y == 0) ? w0 : (blockIdx.y == 1) ? w1 : (blockIdx.y == 2) ? w2 : w3;
  unsigned short* out = (blockIdx.y == 0) ? o0 : (blockIdx.y == 1) ? o1 : (blockIdx.y == 2) ? o2 : o3;
  mxq_body(in, out, b);
}

// ---------------- bf16 MFMA NT GEMM ----------------
// C[m,n] = sum_k A[m,k]*B[n,k] + bias[n]. 128x128 tile, BK=64, 4 waves.
// MODE 0: fp32 C[m][n].  MODE 1: bf16 hi/lo planes [m][n].
// MODE 2: bf16 hi/lo planes transposed per-head: Vt[b][n][s] (n = h*64+d, m = b*1024+s).

template <int MODE>
__global__ __launch_bounds__(256)
void gemm_mfma(const unsigned short* __restrict__ A, const unsigned short* __restrict__ Bw,
               const float* __restrict__ bias, float* __restrict__ C,
               unsigned short* __restrict__ Phi, unsigned short* __restrict__ Plo,
               int M, int N, int K) {
  __shared__ unsigned short sA[128 * 64];
  __shared__ unsigned short sB[128 * 64];
  const int tid = threadIdx.x;
  const int w = tid >> 6, ln = tid & 63;
  const int bm = blockIdx.y * 128, bn = blockIdx.x * 128;
  const int wm = (w >> 1) * 64, wn = (w & 1) * 64;

  f32x4 acc[4][4];
  f32x4 zero = {0.0f, 0.0f, 0.0f, 0.0f};
#pragma unroll
  for (int i = 0; i < 4; ++i)
#pragma unroll
    for (int j = 0; j < 4; ++j) acc[i][j] = zero;

  const int srow = ln >> 3;
  const int gsw  = (ln & 7) ^ srow;

  for (int k0 = 0; k0 < K; k0 += 64) {
    __syncthreads();
#pragma unroll
    for (int q = 0; q < 4; ++q) {
      int row = w * 32 + q * 8 + srow;
      const unsigned short* ga = A  + (size_t)(bm + row) * K + k0 + gsw * 8;
      const unsigned short* gb = Bw + (size_t)(bn + row) * K + k0 + gsw * 8;
      __builtin_amdgcn_global_load_lds(
          (const __attribute__((address_space(1))) unsigned int*)ga,
          (__attribute__((address_space(3))) unsigned int*)(sA + (w * 32 + q * 8) * 64),
          16, 0, 0);
      __builtin_amdgcn_global_load_lds(
          (const __attribute__((address_space(1))) unsigned int*)gb,
          (__attribute__((address_space(3))) unsigned int*)(sB + (w * 32 + q * 8) * 64),
          16, 0, 0);
    }
    __syncthreads();

#pragma unroll
    for (int ks = 0; ks < 2; ++ks) {
      bf16x8 af[4], bf[4];
      const int gq = ks * 4 + (ln >> 4);
#pragma unroll
      for (int t = 0; t < 4; ++t) {
        int m = wm + t * 16 + (ln & 15);
        af[t] = *(const bf16x8*)(sA + m * 64 + ((gq ^ (m & 7)) * 8));
        int n = wn + t * 16 + (ln & 15);
        bf[t] = *(const bf16x8*)(sB + n * 64 + ((gq ^ (n & 7)) * 8));
      }
#pragma unroll
      for (int ti = 0; ti < 4; ++ti)
#pragma unroll
        for (int tj = 0; tj < 4; ++tj)
          acc[ti][tj] = __builtin_amdgcn_mfma_f32_16x16x32_bf16(af[ti], bf[tj], acc[ti][tj], 0, 0, 0);
    }
  }

  const int quad = ln >> 4, col = ln & 15;
#pragma unroll
  for (int ti = 0; ti < 4; ++ti) {
#pragma unroll
    for (int tj = 0; tj < 4; ++tj) {
      int n = bn + wn + tj * 16 + col;
      float bv = bias[n];
      if (MODE == 0) {
#pragma unroll
        for (int i = 0; i < 4; ++i) {
          int m = bm + wm + ti * 16 + quad * 4 + i;
          C[(size_t)m * N + n] = acc[ti][tj][i] + bv;
        }
      } else if (MODE == 1) {
#pragma unroll
        for (int i = 0; i < 4; ++i) {
          int m = bm + wm + ti * 16 + quad * 4 + i;
          float v = acc[ti][tj][i] + bv;
          unsigned short h = f32_to_bf16_rne(v);
          float hf = __uint_as_float((unsigned)h << 16);
          Phi[(size_t)m * N + n] = h;
          Plo[(size_t)m * N + n] = f32_to_bf16_rne(v - hf);
        }
      } else {
        int m0 = bm + wm + ti * 16 + quad * 4;  // 4 consecutive s in one batch
        u16x4 h4, l4;
#pragma unroll
        for (int i = 0; i < 4; ++i) {
          float v = acc[ti][tj][i] + bv;
          unsigned short h = f32_to_bf16_rne(v);
          float hf = __uint_as_float((unsigned)h << 16);
          h4[i] = h;
          l4[i] = f32_to_bf16_rne(v - hf);
        }
        size_t idx = ((size_t)((m0 >> 10) * 1024 + n)) * 1024 + (m0 & 1023);
        *(u16x4*)(Phi + idx) = h4;
        *(u16x4*)(Plo + idx) = l4;
      }
    }
  }
}

// ---------------- MFMA flash attention, fused score+ctx MX quant ----------
// grid (16, 64): WG = (qt, b*16+h); 64 q-rows, kv tiles of 64, 4 waves x 16 q-rows.
// K/V hi/lo staged via global_load_lds (chunk-XOR-swizzled, conflict-free);
// Q fragments loaded directly from global planes. P wave-private LDS (stride 68).

__global__ __launch_bounds__(256)
void attn_kernel(const unsigned short* __restrict__ Qhi, const unsigned short* __restrict__ Qlo,
                 const unsigned short* __restrict__ Khi, const unsigned short* __restrict__ Klo,
                 const unsigned short* __restrict__ Vthi, const unsigned short* __restrict__ Vtlo,
                 unsigned short* __restrict__ ctxq) {
  const int tid = threadIdx.x;
  const int qt = blockIdx.x, bh = blockIdx.y;
  const int b = bh >> 4, h = bh & 15;
  const int w = tid >> 6, ln = tid & 63, quad = ln >> 4, col = ln & 15;

  __shared__ __align__(16) char smem[50176];
  short* sKhi = (short*)smem;           // 4 regions of 64 rows x 64 bf16 = 8192 B
  unsigned int* Pw = (unsigned int*)(smem + 32768) + w * 1088;  // 16 x 68 u32 per wave

  // Q fragments straight from global hi/lo planes (one-time, 4 x 16B per lane)
  bf16x8 qh[2], ql[2];
  {
    const size_t qoff = (size_t)(b * 1024 + qt * 64 + w * 16 + col) * 1024 + h * 64 + quad * 8;
    qh[0] = *(const bf16x8*)(Qhi + qoff);
    qh[1] = *(const bf16x8*)(Qhi + qoff + 32);
    ql[0] = *(const bf16x8*)(Qlo + qoff);
    ql[1] = *(const bf16x8*)(Qlo + qoff + 32);
  }

  // staging assignment: wave w stages plane w into region w
  const unsigned short* gplane = (w == 0) ? Khi : (w == 1) ? Klo : (w == 2) ? Vthi : Vtlo;
  short* splane = sKhi + w * 4096;
  const int r8 = ln >> 3;
  const int ch = (ln & 7) ^ r8;          // swizzled chunk (8 bf16 = 16 B)
  const size_t gbase = (w < 2)
      ? ((size_t)(b * 1024) * 1024 + (size_t)h * 64 + ch * 8)            // + (kt*64+row)*1024
      : ((size_t)(b * 1024 + h * 64) * 1024 + ch * 8);                   // + row*1024 + kt*64

  f32x4 o[4];
  f32x4 zero = {0.0f, 0.0f, 0.0f, 0.0f};
#pragma unroll
  for (int t = 0; t < 4; ++t) o[t] = zero;
  float m_[4], l_[4];
#pragma unroll
  for (int i = 0; i < 4; ++i) { m_[i] = -3.0e38f; l_[i] = 0.0f; }

#pragma unroll 1
  for (int kt = 0; kt < 16; ++kt) {
    __syncthreads();  // prior tile's fragment reads complete before restaging
#pragma unroll
    for (int g = 0; g < 8; ++g) {
      int row = g * 8 + r8;
      const unsigned short* src = gplane + gbase +
          ((w < 2) ? (size_t)(kt * 64 + row) * 1024 : (size_t)row * 1024 + kt * 64);
      __builtin_amdgcn_global_load_lds(
          (const __attribute__((address_space(1))) unsigned int*)src,
          (__attribute__((address_space(3))) unsigned int*)(splane + g * 512),
          16, 0, 0);
    }
    __syncthreads();  // staging visible

    // S = (Qhi+Qlo)·(Khi+Klo)^T, 3 cross terms, then x0.125 (exact pow2)
    f32x4 s[4];
#pragma unroll
    for (int t = 0; t < 4; ++t) s[t] = zero;
#pragma unroll
    for (int t = 0; t < 4; ++t) {
      int n = t * 16 + col;
#pragma unroll
      for (int ks = 0; ks < 2; ++ks) {
        const int gq = ks * 4 + quad;
        bf16x8 kh = *(const bf16x8*)(sKhi +        n * 64 + ((gq ^ (n & 7)) * 8));
        bf16x8 kl = *(const bf16x8*)(sKhi + 4096 + n * 64 + ((gq ^ (n & 7)) * 8));
        s[t] = __builtin_amdgcn_mfma_f32_16x16x32_bf16(ql[ks], kh, s[t], 0, 0, 0);
        s[t] = __builtin_amdgcn_mfma_f32_16x16x32_bf16(qh[ks], kl, s[t], 0, 0, 0);
        s[t] = __builtin_amdgcn_mfma_f32_16x16x32_bf16(qh[ks], kh, s[t], 0, 0, 0);
      }
    }
#pragma unroll
    for (int t = 0; t < 4; ++t)
#pragma unroll
      for (int i = 0; i < 4; ++i) s[t][i] *= 0.125f;

    // MX quantize scores: blocks of 32 kv = frag pairs (0,1) and (2,3)
    float am0[4], am1[4];
#pragma unroll
    for (int i = 0; i < 4; ++i) {
      am0[i] = fmaxf(__builtin_fabsf(s[0][i]), __builtin_fabsf(s[1][i]));
      am1[i] = fmaxf(__builtin_fabsf(s[2][i]), __builtin_fabsf(s[3][i]));
    }
#pragma unroll
    for (int msk = 1; msk <= 8; msk <<= 1)
#pragma unroll
      for (int i = 0; i < 4; ++i) {
        am0[i] = fmaxf(am0[i], __shfl_xor(am0[i], msk, 64));
        am1[i] = fmaxf(am1[i], __shfl_xor(am1[i], msk, 64));
      }
    float mt[4];
#pragma unroll
    for (int i = 0; i < 4; ++i) {
      float sc0, iv0, sc1, iv1;
      mx_scale(am0[i], sc0, iv0);
      mx_scale(am1[i], sc1, iv1);
      float q0 = qdq_e4m3(s[0][i] * iv0) * sc0;
      float q1 = qdq_e4m3(s[1][i] * iv0) * sc0;
      float q2 = qdq_e4m3(s[2][i] * iv1) * sc1;
      float q3 = qdq_e4m3(s[3][i] * iv1) * sc1;
      s[0][i] = q0; s[1][i] = q1; s[2][i] = q2; s[3][i] = q3;
      mt[i] = fmaxf(fmaxf(q0, q1), fmaxf(q2, q3));
    }
#pragma unroll
    for (int msk = 1; msk <= 8; msk <<= 1)
#pragma unroll
      for (int i = 0; i < 4; ++i) mt[i] = fmaxf(mt[i], __shfl_xor(mt[i], msk, 64));

    // online softmax
#pragma unroll
    for (int i = 0; i < 4; ++i) {
      float mnew  = fmaxf(m_[i], mt[i]);
      float alpha = __expf(m_[i] - mnew);
      m_[i] = mnew;
      l_[i] *= alpha;
#pragma unroll
      for (int t = 0; t < 4; ++t) o[t][i] *= alpha;
#pragma unroll
      for (int t = 0; t < 4; ++t) {
        float p = __expf(s[t][i] - mnew);
        s[t][i] = p;
        l_[i] += p;
      }
    }

    // P: C-layout -> wave-private LDS (hi/lo packed u32) -> A-layout fragments
#pragma unroll
    for (int t = 0; t < 4; ++t)
#pragma unroll
      for (int i = 0; i < 4; ++i) {
        float p = s[t][i];
        unsigned short ph = f32_to_bf16_rne(p);
        float pf = __uint_as_float((unsigned)ph << 16);
        unsigned short pl = f32_to_bf16_rne(p - pf);
        Pw[(quad * 4 + i) * 68 + t * 16 + col] = ((unsigned)ph << 16) | pl;
      }
    bf16x8 pah[2], pal[2];
#pragma unroll
    for (int ks = 0; ks < 2; ++ks) {
      const unsigned int* pr = Pw + col * 68 + ks * 32 + quad * 8;
      uint4 u0 = *(const uint4*)pr;
      uint4 u1 = *(const uint4*)(pr + 4);
      unsigned int uu[8] = {u0.x, u0.y, u0.z, u0.w, u1.x, u1.y, u1.z, u1.w};
      bf16x8 hh, llv;
#pragma unroll
      for (int e = 0; e < 8; ++e) {
        hh[e]  = (short)(uu[e] >> 16);
        llv[e] = (short)(uu[e] & 0xffffu);
      }
      pah[ks] = hh; pal[ks] = llv;
    }

    // O += (Phi+Plo)·(Vhi+Vlo), 3 cross terms
#pragma unroll
    for (int nt = 0; nt < 4; ++nt) {
      int n = nt * 16 + col;
#pragma unroll
      for (int ks = 0; ks < 2; ++ks) {
        const int gq = ks * 4 + quad;
        bf16x8 vh = *(const bf16x8*)(sKhi +  8192 + n * 64 + ((gq ^ (n & 7)) * 8));
        bf16x8 vl = *(const bf16x8*)(sKhi + 12288 + n * 64 + ((gq ^ (n & 7)) * 8));
        o[nt] = __builtin_amdgcn_mfma_f32_16x16x32_bf16(pal[ks], vh, o[nt], 0, 0, 0);
        o[nt] = __builtin_amdgcn_mfma_f32_16x16x32_bf16(pah[ks], vl, o[nt], 0, 0, 0);
        o[nt] = __builtin_amdgcn_mfma_f32_16x16x32_bf16(pah[ks], vh, o[nt], 0, 0, 0);
      }
    }
  }

  // normalize + fused ctx MX quant (blocks of 32 along E = frag pairs) -> bf16
#pragma unroll
  for (int msk = 1; msk <= 8; msk <<= 1)
#pragma unroll
    for (int i = 0; i < 4; ++i) l_[i] += __shfl_xor(l_[i], msk, 64);
  float cam0[4], cam1[4];
#pragma unroll
  for (int i = 0; i < 4; ++i) {
    float invl = 1.0f / l_[i];
#pragma unroll
    for (int t = 0; t < 4; ++t) o[t][i] *= invl;
    cam0[i] = fmaxf(__builtin_fabsf(o[0][i]), __builtin_fabsf(o[1][i]));
    cam1[i] = fmaxf(__builtin_fabsf(o[2][i]), __builtin_fabsf(o[3][i]));
  }
#pragma unroll
  for (int msk = 1; msk <= 8; msk <<= 1)
#pragma unroll
    for (int i = 0; i < 4; ++i) {
      cam0[i] = fmaxf(cam0[i], __shfl_xor(cam0[i], msk, 64));
      cam1[i] = fmaxf(cam1[i], __shfl_xor(cam1[i], msk, 64));
    }
#pragma unroll
  for (int i = 0; i < 4; ++i) {
    float sc0, iv0, sc1, iv1;
    mx_scale(cam0[i], sc0, iv0);
    mx_scale(cam1[i], sc1, iv1);
    int rowg = b * 1024 + qt * 64 + w * 16 + quad * 4 + i;
#pragma unroll
    for (int t = 0; t < 4; ++t) {
      float scq = (t < 2) ? sc0 : sc1;
      float ivq = (t < 2) ? iv0 : iv1;
      float q = qdq_e4m3(o[t][i] * ivq) * scq;
      ctxq[(size_t)rowg * 1024 + h * 64 + t * 16 + col] =
          (unsigned short)(__float_as_uint(q) >> 16);  // exact bf16
    }
  }
}

// ---------------- launch ----------------

extern "C" void kernel_launch(void* const* d_in, const int* in_sizes, int n_in,
                              void* d_out, int out_size, void* d_ws, size_t ws_size,
                              hipStream_t stream) {
  (void)in_sizes; (void)n_in; (void)out_size; (void)ws_size;
  const float* x  = (const float*)d_in[0];
  const float* Wq = (const float*)d_in[1];
  const float* bq = (const float*)d_in[2];
  const float* Wk = (const float*)d_in[3];
  const float* bk = (const float*)d_in[4];
  const float* Wv = (const float*)d_in[5];
  const float* bv = (const float*)d_in[6];
  const float* Wo = (const float*)d_in[7];
  const float* bo = (const float*)d_in[8];

  char* wsb = (char*)d_ws;
  const size_t MB = (size_t)1 << 20;
  unsigned short* XQb   = (unsigned short*)(wsb + 0);
  unsigned short* WQb   = (unsigned short*)(wsb + 8 * MB);
  unsigned short* WKb   = (unsigned short*)(wsb + 10 * MB);
  unsigned short* WVb   = (unsigned short*)(wsb + 12 * MB);
  unsigned short* WOb   = (unsigned short*)(wsb + 14 * MB);
  unsigned short* Qhi   = (unsigned short*)(wsb + 16 * MB);
  unsigned short* Qlo   = (unsigned short*)(wsb + 24 * MB);
  unsigned short* Khi   = (unsigned short*)(wsb + 32 * MB);
  unsigned short* Klo   = (unsigned short*)(wsb + 40 * MB);
  unsigned short* Vthi  = (unsigned short*)(wsb + 48 * MB);
  unsigned short* Vtlo  = (unsigned short*)(wsb + 56 * MB);
  unsigned short* CTXQb = XQb;  // reuse: XQ dead after V projection

  const int nblk_x = NROWS * E_DIM / 32;  // 131072
  const int nblk_w = E_DIM * E_DIM / 32;  // 32768

  mxq_kernel<<<nblk_x / 256, 256, 0, stream>>>(x, XQb, nblk_x);
  mxq4_kernel<<<dim3(nblk_w / 256, 4), 256, 0, stream>>>(Wq, Wk, Wv, Wo, WQb, WKb, WVb, WOb, nblk_w);

  dim3 ggrid(E_DIM / 128, NROWS / 128);  // (8, 32)
  gemm_mfma<1><<<ggrid, 256, 0, stream>>>(XQb, WQb, bq, nullptr, Qhi,  Qlo,  NROWS, E_DIM, E_DIM);
  gemm_mfma<1><<<ggrid, 256, 0, stream>>>(XQb, WKb, bk, nullptr, Khi,  Klo,  NROWS, E_DIM, E_DIM);
  gemm_mfma<2><<<ggrid, 256, 0, stream>>>(XQb, WVb, bv, nullptr, Vthi, Vtlo, NROWS, E_DIM, E_DIM);

  dim3 agrid(S_LEN / 64, BATCH * NH);  // (16, 64)
  attn_kernel<<<agrid, 256, 0, stream>>>(Qhi, Qlo, Khi, Klo, Vthi, Vtlo, CTXQb);

  gemm_mfma<0><<<ggrid, 256, 0, stream>>>(CTXQb, WOb, bo, (float*)d_out, nullptr, nullptr,
                                          NROWS, E_DIM, E_DIM);
}

// Round 8
// 279.018 us; speedup vs baseline: 8.2369x; 1.1608x over previous
//
#include <hip/hip_runtime.h>
#include <hip/hip_bf16.h>
#include <cstdint>
#include <cstddef>

// MXAttention: B=4, S=1024, E=1024, H=16, D=64. fp32 in/out.
// MX quant: blocks of 32 along last/contraction dim, scale=2^(floor(log2(amax))-8),
// e4m3 grid == OCP e4m3fn. qdq = pre-clamp to +-448 then HW v_cvt_pk_fp8_f32 /
// v_cvt_f32_fp8 (RNE). Pre-clamp+convert == reference round-then-clip (proof:
// (448,464] rounds half-even down to 448; >464 rounds to 480 then clips to 448).
//
// GEMMs: quantized operands are e4m3 x pow2 => exactly bf16 => bf16 MFMA, fp32 acc.
// Q/K/V GEMM epilogues emit results pre-split into bf16 hi+lo planes (Q pre-scaled
// by 0.125, exact); attention uses 3 cross-term MFMAs (lo*lo dropped, ~2^-16).
// V planes stored transposed (Vt[b,h,d,s]). K/V staged via global_load_lds.
//
// ws layout (bytes):
//   [ 0, 8)MB  XQb  bf16 quantized input; later reused as CTXQb
//   [ 8,16)MB  WQb/WKb/WVb/WOb (2 MB each)
//   [16,24) Qhi [24,32) Qlo   [32,40) Khi [40,48) Klo   [48,56) Vthi [56,64) Vtlo

#define S_LEN 1024
#define E_DIM 1024
#define NH    16
#define DH    64
#define BATCH 4
#define NROWS (BATCH * S_LEN)  // 4096

typedef short          bf16x8  __attribute__((ext_vector_type(8)));
typedef float          f32x4   __attribute__((ext_vector_type(4)));
typedef unsigned short u16x8   __attribute__((ext_vector_type(8)));
typedef unsigned short u16x4   __attribute__((ext_vector_type(4)));

// ---------------- MX quant helpers ----------------

// scale = 2^(clamp(floor(log2(amax))-8, -126, 126)), 1.0 if amax==0.
// (ref clamps at +-127; amax < 2^-118 or > 2^134 never occurs for this data.)
__device__ __forceinline__ void mx_scale_bits(float amax, float& scale, float& inv) {
  int eb = (int)(__float_as_uint(amax) >> 23);  // biased exponent
  int sb = eb - 8;
  sb = sb < 1 ? 1 : (sb > 253 ? 253 : sb);
  float sc = __uint_as_float((unsigned)sb << 23);
  float iv = __uint_as_float((unsigned)(254 - sb) << 23);
  bool nz = (amax > 0.0f);
  scale = nz ? sc : 1.0f;
  inv   = nz ? iv : 1.0f;
}

// round a,b to the e4m3fn grid: pre-clamp +-448 (== ref round-then-clip), HW RNE cvt.
__device__ __forceinline__ void qdq2(float& a, float& b) {
  a = fminf(fmaxf(a, -448.0f), 448.0f);
  b = fminf(fmaxf(b, -448.0f), 448.0f);
  int p = __builtin_amdgcn_cvt_pk_fp8_f32(a, b, 0, false);
  a = __builtin_amdgcn_cvt_f32_fp8(p, 0);
  b = __builtin_amdgcn_cvt_f32_fp8(p, 1);
}

__device__ __forceinline__ unsigned short f32_to_bf16_rne(float f) {
  unsigned u = __float_as_uint(f);
  unsigned r = 0x7FFFu + ((u >> 16) & 1u);
  return (unsigned short)((u + r) >> 16);
}

// ---------------- quant kernels: fp32 in -> bf16 out (exact) ----------------

__device__ __forceinline__ void mxq_body(const float* __restrict__ in,
                                         unsigned short* __restrict__ out, int b) {
  const float4* p = (const float4*)(in + (size_t)b * 32);
  float v[32];
#pragma unroll
  for (int g = 0; g < 8; ++g) {
    float4 t = p[g];
    v[g * 4 + 0] = t.x; v[g * 4 + 1] = t.y; v[g * 4 + 2] = t.z; v[g * 4 + 3] = t.w;
  }
  float amax = 0.0f;
#pragma unroll
  for (int i = 0; i < 32; ++i) amax = fmaxf(amax, __builtin_fabsf(v[i]));
  float scale, inv;
  mx_scale_bits(amax, scale, inv);
  u16x8* q = (u16x8*)(out + (size_t)b * 32);
#pragma unroll
  for (int g = 0; g < 4; ++g) {
    u16x8 o;
#pragma unroll
    for (int e = 0; e < 8; e += 2) {
      float a = v[g * 8 + e] * inv, c = v[g * 8 + e + 1] * inv;
      qdq2(a, c);
      o[e]     = (unsigned short)(__float_as_uint(a * scale) >> 16);  // exact bf16
      o[e + 1] = (unsigned short)(__float_as_uint(c * scale) >> 16);
    }
    q[g] = o;
  }
}

__global__ __launch_bounds__(256)
void mxq_kernel(const float* __restrict__ in, unsigned short* __restrict__ out, int nblk) {
  int b = blockIdx.x * 256 + threadIdx.x;
  if (b < nblk) mxq_body(in, out, b);
}

__global__ __launch_bounds__(256)
void mxq4_kernel(const float* __restrict__ w0, const float* __restrict__ w1,
                 const float* __restrict__ w2, const float* __restrict__ w3,
                 unsigned short* __restrict__ o0, unsigned short* __restrict__ o1,
                 unsigned short* __restrict__ o2, unsigned short* __restrict__ o3,
                 int nblk) {
  int b = blockIdx.x * 256 + threadIdx.x;
  if (b >= nblk) return;
  const float* in = (blockIdx.y == 0) ? w0 : (blockIdx.y == 1) ? w1 : (blockIdx.y == 2) ? w2 : w3;
  unsigned short* out = (blockIdx.y == 0) ? o0 : (blockIdx.y == 1) ? o1 : (blockIdx.y == 2) ? o2 : o3;
  mxq_body(in, out, b);
}

// ---------------- fused Q/K/V bf16 MFMA NT GEMM ----------------
// grid (8, 32, 3): z selects weight/bias/output. 128x128 tile, BK=64, 4 waves.
// z=0: Q hi/lo planes pre-scaled 0.125. z=1: K hi/lo planes. z=2: Vt hi/lo planes.

__global__ __launch_bounds__(256)
void gemm_qkv(const unsigned short* __restrict__ XQ,
              const unsigned short* __restrict__ Wqw, const unsigned short* __restrict__ Wkw,
              const unsigned short* __restrict__ Wvw,
              const float* __restrict__ bq, const float* __restrict__ bk,
              const float* __restrict__ bv,
              unsigned short* __restrict__ Qhi, unsigned short* __restrict__ Qlo,
              unsigned short* __restrict__ Khi, unsigned short* __restrict__ Klo,
              unsigned short* __restrict__ Vthi, unsigned short* __restrict__ Vtlo) {
  const int z = blockIdx.z;
  const unsigned short* Bw = (z == 0) ? Wqw : (z == 1) ? Wkw : Wvw;
  const float* bias = (z == 0) ? bq : (z == 1) ? bk : bv;
  unsigned short* Phi = (z == 0) ? Qhi : (z == 1) ? Khi : Vthi;
  unsigned short* Plo = (z == 0) ? Qlo : (z == 1) ? Klo : Vtlo;
  const float pre = (z == 0) ? 0.125f : 1.0f;

  __shared__ unsigned short sA[128 * 64];
  __shared__ unsigned short sB[128 * 64];
  const int tid = threadIdx.x;
  const int w = tid >> 6, ln = tid & 63;
  const int bm = blockIdx.y * 128, bn = blockIdx.x * 128;
  const int wm = (w >> 1) * 64, wn = (w & 1) * 64;
  const int quad = ln >> 4, col = ln & 15;

  f32x4 acc[4][4];
  f32x4 zero = {0.0f, 0.0f, 0.0f, 0.0f};
#pragma unroll
  for (int i = 0; i < 4; ++i)
#pragma unroll
    for (int j = 0; j < 4; ++j) acc[i][j] = zero;

  const int srow = ln >> 3;
  const int gsw  = (ln & 7) ^ srow;
  const int xo0 = (quad ^ (ln & 7)) * 8;
  const int xo1 = ((quad ^ 4) ^ (ln & 7)) * 8;

  for (int k0 = 0; k0 < 1024; k0 += 64) {
    __syncthreads();
#pragma unroll
    for (int q = 0; q < 4; ++q) {
      int row = w * 32 + q * 8 + srow;
      const unsigned short* ga = XQ + (size_t)(bm + row) * 1024 + k0 + gsw * 8;
      const unsigned short* gb = Bw + (size_t)(bn + row) * 1024 + k0 + gsw * 8;
      __builtin_amdgcn_global_load_lds(
          (const __attribute__((address_space(1))) unsigned int*)ga,
          (__attribute__((address_space(3))) unsigned int*)(sA + (w * 32 + q * 8) * 64),
          16, 0, 0);
      __builtin_amdgcn_global_load_lds(
          (const __attribute__((address_space(1))) unsigned int*)gb,
          (__attribute__((address_space(3))) unsigned int*)(sB + (w * 32 + q * 8) * 64),
          16, 0, 0);
    }
    __syncthreads();

#pragma unroll
    for (int ks = 0; ks < 2; ++ks) {
      const int xo = ks ? xo1 : xo0;
      bf16x8 af[4], bf[4];
#pragma unroll
      for (int t = 0; t < 4; ++t) {
        af[t] = *(const bf16x8*)(sA + (wm + t * 16 + col) * 64 + xo);
        bf[t] = *(const bf16x8*)(sB + (wn + t * 16 + col) * 64 + xo);
      }
#pragma unroll
      for (int ti = 0; ti < 4; ++ti)
#pragma unroll
        for (int tj = 0; tj < 4; ++tj)
          acc[ti][tj] = __builtin_amdgcn_mfma_f32_16x16x32_bf16(af[ti], bf[tj], acc[ti][tj], 0, 0, 0);
    }
  }

#pragma unroll
  for (int ti = 0; ti < 4; ++ti) {
#pragma unroll
    for (int tj = 0; tj < 4; ++tj) {
      int n = bn + wn + tj * 16 + col;
      float bv_ = bias[n];
      if (z != 2) {
#pragma unroll
        for (int i = 0; i < 4; ++i) {
          int m = bm + wm + ti * 16 + quad * 4 + i;
          float v = (acc[ti][tj][i] + bv_) * pre;
          unsigned short h = f32_to_bf16_rne(v);
          float hf = __uint_as_float((unsigned)h << 16);
          Phi[(size_t)m * 1024 + n] = h;
          Plo[(size_t)m * 1024 + n] = f32_to_bf16_rne(v - hf);
        }
      } else {
        int m0 = bm + wm + ti * 16 + quad * 4;  // 4 consecutive s in one batch
        u16x4 h4, l4;
#pragma unroll
        for (int i = 0; i < 4; ++i) {
          float v = acc[ti][tj][i] + bv_;
          unsigned short h = f32_to_bf16_rne(v);
          float hf = __uint_as_float((unsigned)h << 16);
          h4[i] = h;
          l4[i] = f32_to_bf16_rne(v - hf);
        }
        size_t idx = ((size_t)((m0 >> 10) * 1024 + n)) * 1024 + (m0 & 1023);
        *(u16x4*)(Phi + idx) = h4;
        *(u16x4*)(Plo + idx) = l4;
      }
    }
  }
}

// ---------------- O-projection GEMM: 64x128 tile (512 WGs, 2/CU) ----------------

__global__ __launch_bounds__(256)
void gemm_o(const unsigned short* __restrict__ A, const unsigned short* __restrict__ Bw,
            const float* __restrict__ bias, float* __restrict__ C) {
  __shared__ unsigned short sA[64 * 64];
  __shared__ unsigned short sB[128 * 64];
  const int tid = threadIdx.x;
  const int w = tid >> 6, ln = tid & 63;
  const int bm = blockIdx.y * 64, bn = blockIdx.x * 128;
  const int wr = (w >> 1) * 32, wc = (w & 1) * 64;
  const int quad = ln >> 4, col = ln & 15;

  f32x4 acc[2][4];
  f32x4 zero = {0.0f, 0.0f, 0.0f, 0.0f};
#pragma unroll
  for (int i = 0; i < 2; ++i)
#pragma unroll
    for (int j = 0; j < 4; ++j) acc[i][j] = zero;

  const int srow = ln >> 3;
  const int gsw  = (ln & 7) ^ srow;
  const int xo0 = (quad ^ (ln & 7)) * 8;
  const int xo1 = ((quad ^ 4) ^ (ln & 7)) * 8;

  for (int k0 = 0; k0 < 1024; k0 += 64) {
    __syncthreads();
#pragma unroll
    for (int qa = 0; qa < 2; ++qa) {
      int row = w * 16 + qa * 8 + srow;
      __builtin_amdgcn_global_load_lds(
          (const __attribute__((address_space(1))) unsigned int*)(A + (size_t)(bm + row) * 1024 + k0 + gsw * 8),
          (__attribute__((address_space(3))) unsigned int*)(sA + (w * 16 + qa * 8) * 64),
          16, 0, 0);
    }
#pragma unroll
    for (int qb = 0; qb < 4; ++qb) {
      int row = w * 32 + qb * 8 + srow;
      __builtin_amdgcn_global_load_lds(
          (const __attribute__((address_space(1))) unsigned int*)(Bw + (size_t)(bn + row) * 1024 + k0 + gsw * 8),
          (__attribute__((address_space(3))) unsigned int*)(sB + (w * 32 + qb * 8) * 64),
          16, 0, 0);
    }
    __syncthreads();

#pragma unroll
    for (int ks = 0; ks < 2; ++ks) {
      const int xo = ks ? xo1 : xo0;
      bf16x8 af[2], bf[4];
#pragma unroll
      for (int t = 0; t < 2; ++t)
        af[t] = *(const bf16x8*)(sA + (wr + t * 16 + col) * 64 + xo);
#pragma unroll
      for (int t = 0; t < 4; ++t)
        bf[t] = *(const bf16x8*)(sB + (wc + t * 16 + col) * 64 + xo);
#pragma unroll
      for (int ti = 0; ti < 2; ++ti)
#pragma unroll
        for (int tj = 0; tj < 4; ++tj)
          acc[ti][tj] = __builtin_amdgcn_mfma_f32_16x16x32_bf16(af[ti], bf[tj], acc[ti][tj], 0, 0, 0);
    }
  }

#pragma unroll
  for (int ti = 0; ti < 2; ++ti) {
#pragma unroll
    for (int tj = 0; tj < 4; ++tj) {
      int n = bn + wc + tj * 16 + col;
      float bv_ = bias[n];
#pragma unroll
      for (int i = 0; i < 4; ++i) {
        int m = bm + wr + ti * 16 + quad * 4 + i;
        C[(size_t)m * 1024 + n] = acc[ti][tj][i] + bv_;
      }
    }
  }
}

// ---------------- MFMA flash attention, fused score+ctx MX quant ----------
// grid (16, 64): WG = (qt, b*16+h); 64 q-rows, kv tiles of 64, 4 waves x 16 q-rows.
// K/V hi/lo staged via global_load_lds (chunk-XOR-swizzled); Q fragments from
// global planes (pre-scaled 0.125). P wave-private LDS (stride 68).

__global__ __launch_bounds__(256)
void attn_kernel(const unsigned short* __restrict__ Qhi, const unsigned short* __restrict__ Qlo,
                 const unsigned short* __restrict__ Khi, const unsigned short* __restrict__ Klo,
                 const unsigned short* __restrict__ Vthi, const unsigned short* __restrict__ Vtlo,
                 unsigned short* __restrict__ ctxq) {
  const int tid = threadIdx.x;
  const int qt = blockIdx.x, bh = blockIdx.y;
  const int b = bh >> 4, h = bh & 15;
  const int w = tid >> 6, ln = tid & 63, quad = ln >> 4, col = ln & 15;

  __shared__ __align__(16) char smem[50176];
  short* sKhi = (short*)smem;           // 4 regions of 64 rows x 64 bf16 = 8192 B
  unsigned int* Pw = (unsigned int*)(smem + 32768) + w * 1088;  // 16 x 68 u32 per wave

  // Q fragments straight from global hi/lo planes (one-time, 4 x 16B per lane)
  bf16x8 qh[2], ql[2];
  {
    const size_t qoff = (size_t)(b * 1024 + qt * 64 + w * 16 + col) * 1024 + h * 64 + quad * 8;
    qh[0] = *(const bf16x8*)(Qhi + qoff);
    qh[1] = *(const bf16x8*)(Qhi + qoff + 32);
    ql[0] = *(const bf16x8*)(Qlo + qoff);
    ql[1] = *(const bf16x8*)(Qlo + qoff + 32);
  }

  // staging: wave w stages plane w into region w; pointer advanced across kt
  const unsigned short* gplane = (w == 0) ? Khi : (w == 1) ? Klo : (w == 2) ? Vthi : Vtlo;
  short* splane = sKhi + w * 4096;
  const int r8 = ln >> 3;
  const int ch = (ln & 7) ^ r8;
  const unsigned short* bp = gplane + (size_t)r8 * 1024 + ch * 8 +
      ((w < 2) ? ((size_t)(b * 1024) * 1024 + (size_t)h * 64)
               : ((size_t)(b * 1024 + h * 64) * 1024));
  const int ktstep = (w < 2) ? 65536 : 64;

  const int xo0 = (quad ^ (col & 7)) * 8;
  const int xo1 = ((quad ^ 4) ^ (col & 7)) * 8;

  f32x4 o[4];
  f32x4 zero = {0.0f, 0.0f, 0.0f, 0.0f};
#pragma unroll
  for (int t = 0; t < 4; ++t) o[t] = zero;
  float m_[4], l_[4];
#pragma unroll
  for (int i = 0; i < 4; ++i) { m_[i] = -3.0e38f; l_[i] = 0.0f; }

#pragma unroll 1
  for (int kt = 0; kt < 16; ++kt) {
    __syncthreads();  // prior tile's fragment reads complete before restaging
#pragma unroll
    for (int g = 0; g < 8; ++g) {
      __builtin_amdgcn_global_load_lds(
          (const __attribute__((address_space(1))) unsigned int*)(bp + g * 8192),
          (__attribute__((address_space(3))) unsigned int*)(splane + g * 512),
          16, 0, 0);
    }
    bp += ktstep;
    __syncthreads();  // staging visible

    // S = (Qhi+Qlo)·(Khi+Klo)^T, 3 cross terms (Q pre-scaled by 1/8)
    f32x4 s[4];
#pragma unroll
    for (int t = 0; t < 4; ++t) s[t] = zero;
#pragma unroll
    for (int t = 0; t < 4; ++t) {
      const int rb = (t * 16 + col) * 64;
#pragma unroll
      for (int ks = 0; ks < 2; ++ks) {
        const int xo = ks ? xo1 : xo0;
        bf16x8 kh = *(const bf16x8*)(sKhi +        rb + xo);
        bf16x8 kl = *(const bf16x8*)(sKhi + 4096 + rb + xo);
        s[t] = __builtin_amdgcn_mfma_f32_16x16x32_bf16(ql[ks], kh, s[t], 0, 0, 0);
        s[t] = __builtin_amdgcn_mfma_f32_16x16x32_bf16(qh[ks], kl, s[t], 0, 0, 0);
        s[t] = __builtin_amdgcn_mfma_f32_16x16x32_bf16(qh[ks], kh, s[t], 0, 0, 0);
      }
    }

    // MX quantize scores: blocks of 32 kv = frag pairs (0,1) and (2,3)
    float am0[4], am1[4];
#pragma unroll
    for (int i = 0; i < 4; ++i) {
      am0[i] = fmaxf(__builtin_fabsf(s[0][i]), __builtin_fabsf(s[1][i]));
      am1[i] = fmaxf(__builtin_fabsf(s[2][i]), __builtin_fabsf(s[3][i]));
    }
#pragma unroll
    for (int msk = 1; msk <= 8; msk <<= 1)
#pragma unroll
      for (int i = 0; i < 4; ++i) {
        am0[i] = fmaxf(am0[i], __shfl_xor(am0[i], msk, 64));
        am1[i] = fmaxf(am1[i], __shfl_xor(am1[i], msk, 64));
      }
    float mt[4];
#pragma unroll
    for (int i = 0; i < 4; ++i) {
      float sc0, iv0, sc1, iv1;
      mx_scale_bits(am0[i], sc0, iv0);
      mx_scale_bits(am1[i], sc1, iv1);
      float q0 = s[0][i] * iv0, q1 = s[1][i] * iv0;
      float q2 = s[2][i] * iv1, q3 = s[3][i] * iv1;
      qdq2(q0, q1);
      qdq2(q2, q3);
      q0 *= sc0; q1 *= sc0; q2 *= sc1; q3 *= sc1;
      s[0][i] = q0; s[1][i] = q1; s[2][i] = q2; s[3][i] = q3;
      mt[i] = fmaxf(fmaxf(q0, q1), fmaxf(q2, q3));
    }
#pragma unroll
    for (int msk = 1; msk <= 8; msk <<= 1)
#pragma unroll
      for (int i = 0; i < 4; ++i) mt[i] = fmaxf(mt[i], __shfl_xor(mt[i], msk, 64));

    // online softmax
#pragma unroll
    for (int i = 0; i < 4; ++i) {
      float mnew  = fmaxf(m_[i], mt[i]);
      float alpha = __expf(m_[i] - mnew);
      m_[i] = mnew;
      l_[i] *= alpha;
#pragma unroll
      for (int t = 0; t < 4; ++t) o[t][i] *= alpha;
#pragma unroll
      for (int t = 0; t < 4; ++t) {
        float p = __expf(s[t][i] - mnew);
        s[t][i] = p;
        l_[i] += p;
      }
    }

    // P: C-layout -> wave-private LDS (hi/lo packed u32) -> A-layout fragments
#pragma unroll
    for (int t = 0; t < 4; ++t)
#pragma unroll
      for (int i = 0; i < 4; ++i) {
        float p = s[t][i];
        unsigned short ph = f32_to_bf16_rne(p);
        float pf = __uint_as_float((unsigned)ph << 16);
        unsigned short pl = f32_to_bf16_rne(p - pf);
        Pw[(quad * 4 + i) * 68 + t * 16 + col] = ((unsigned)ph << 16) | pl;
      }
    bf16x8 pah[2], pal[2];
#pragma unroll
    for (int ks = 0; ks < 2; ++ks) {
      const unsigned int* pr = Pw + col * 68 + ks * 32 + quad * 8;
      uint4 u0 = *(const uint4*)pr;
      uint4 u1 = *(const uint4*)(pr + 4);
      unsigned int uu[8] = {u0.x, u0.y, u0.z, u0.w, u1.x, u1.y, u1.z, u1.w};
      bf16x8 hh, llv;
#pragma unroll
      for (int e = 0; e < 8; ++e) {
        hh[e]  = (short)(uu[e] >> 16);
        llv[e] = (short)(uu[e] & 0xffffu);
      }
      pah[ks] = hh; pal[ks] = llv;
    }

    // O += (Phi+Plo)·(Vhi+Vlo), 3 cross terms
#pragma unroll
    for (int nt = 0; nt < 4; ++nt) {
      const int rb = (nt * 16 + col) * 64;
#pragma unroll
      for (int ks = 0; ks < 2; ++ks) {
        const int xo = ks ? xo1 : xo0;
        bf16x8 vh = *(const bf16x8*)(sKhi +  8192 + rb + xo);
        bf16x8 vl = *(const bf16x8*)(sKhi + 12288 + rb + xo);
        o[nt] = __builtin_amdgcn_mfma_f32_16x16x32_bf16(pal[ks], vh, o[nt], 0, 0, 0);
        o[nt] = __builtin_amdgcn_mfma_f32_16x16x32_bf16(pah[ks], vl, o[nt], 0, 0, 0);
        o[nt] = __builtin_amdgcn_mfma_f32_16x16x32_bf16(pah[ks], vh, o[nt], 0, 0, 0);
      }
    }
  }

  // normalize + fused ctx MX quant (blocks of 32 along E = frag pairs) -> bf16
#pragma unroll
  for (int msk = 1; msk <= 8; msk <<= 1)
#pragma unroll
    for (int i = 0; i < 4; ++i) l_[i] += __shfl_xor(l_[i], msk, 64);
  float cam0[4], cam1[4];
#pragma unroll
  for (int i = 0; i < 4; ++i) {
    float invl = 1.0f / l_[i];
#pragma unroll
    for (int t = 0; t < 4; ++t) o[t][i] *= invl;
    cam0[i] = fmaxf(__builtin_fabsf(o[0][i]), __builtin_fabsf(o[1][i]));
    cam1[i] = fmaxf(__builtin_fabsf(o[2][i]), __builtin_fabsf(o[3][i]));
  }
#pragma unroll
  for (int msk = 1; msk <= 8; msk <<= 1)
#pragma unroll
    for (int i = 0; i < 4; ++i) {
      cam0[i] = fmaxf(cam0[i], __shfl_xor(cam0[i], msk, 64));
      cam1[i] = fmaxf(cam1[i], __shfl_xor(cam1[i], msk, 64));
    }
#pragma unroll
  for (int i = 0; i < 4; ++i) {
    float sc0, iv0, sc1, iv1;
    mx_scale_bits(cam0[i], sc0, iv0);
    mx_scale_bits(cam1[i], sc1, iv1);
    float q0 = o[0][i] * iv0, q1 = o[1][i] * iv0;
    float q2 = o[2][i] * iv1, q3 = o[3][i] * iv1;
    qdq2(q0, q1);
    qdq2(q2, q3);
    q0 *= sc0; q1 *= sc0; q2 *= sc1; q3 *= sc1;
    int rowg = b * 1024 + qt * 64 + w * 16 + quad * 4 + i;
    size_t base = (size_t)rowg * 1024 + h * 64 + col;
    ctxq[base +  0] = (unsigned short)(__float_as_uint(q0) >> 16);
    ctxq[base + 16] = (unsigned short)(__float_as_uint(q1) >> 16);
    ctxq[base + 32] = (unsigned short)(__float_as_uint(q2) >> 16);
    ctxq[base + 48] = (unsigned short)(__float_as_uint(q3) >> 16);
  }
}

// ---------------- launch ----------------

extern "C" void kernel_launch(void* const* d_in, const int* in_sizes, int n_in,
                              void* d_out, int out_size, void* d_ws, size_t ws_size,
                              hipStream_t stream) {
  (void)in_sizes; (void)n_in; (void)out_size; (void)ws_size;
  const float* x  = (const float*)d_in[0];
  const float* Wq = (const float*)d_in[1];
  const float* bq = (const float*)d_in[2];
  const float* Wk = (const float*)d_in[3];
  const float* bk = (const float*)d_in[4];
  const float* Wv = (const float*)d_in[5];
  const float* bv = (const float*)d_in[6];
  const float* Wo = (const float*)d_in[7];
  const float* bo = (const float*)d_in[8];

  char* wsb = (char*)d_ws;
  const size_t MB = (size_t)1 << 20;
  unsigned short* XQb   = (unsigned short*)(wsb + 0);
  unsigned short* WQb   = (unsigned short*)(wsb + 8 * MB);
  unsigned short* WKb   = (unsigned short*)(wsb + 10 * MB);
  unsigned short* WVb   = (unsigned short*)(wsb + 12 * MB);
  unsigned short* WOb   = (unsigned short*)(wsb + 14 * MB);
  unsigned short* Qhi   = (unsigned short*)(wsb + 16 * MB);
  unsigned short* Qlo   = (unsigned short*)(wsb + 24 * MB);
  unsigned short* Khi   = (unsigned short*)(wsb + 32 * MB);
  unsigned short* Klo   = (unsigned short*)(wsb + 40 * MB);
  unsigned short* Vthi  = (unsigned short*)(wsb + 48 * MB);
  unsigned short* Vtlo  = (unsigned short*)(wsb + 56 * MB);
  unsigned short* CTXQb = XQb;  // reuse: XQ dead after V projection

  const int nblk_x = NROWS * E_DIM / 32;  // 131072
  const int nblk_w = E_DIM * E_DIM / 32;  // 32768

  mxq_kernel<<<nblk_x / 256, 256, 0, stream>>>(x, XQb, nblk_x);
  mxq4_kernel<<<dim3(nblk_w / 256, 4), 256, 0, stream>>>(Wq, Wk, Wv, Wo, WQb, WKb, WVb, WOb, nblk_w);

  dim3 qkvgrid(E_DIM / 128, NROWS / 128, 3);  // (8, 32, 3) = 768 WGs
  gemm_qkv<<<qkvgrid, 256, 0, stream>>>(XQb, WQb, WKb, WVb, bq, bk, bv,
                                        Qhi, Qlo, Khi, Klo, Vthi, Vtlo);

  dim3 agrid(S_LEN / 64, BATCH * NH);  // (16, 64)
  attn_kernel<<<agrid, 256, 0, stream>>>(Qhi, Qlo, Khi, Klo, Vthi, Vtlo, CTXQb);

  dim3 ogrid(E_DIM / 128, NROWS / 64);  // (8, 64) = 512 WGs
  gemm_o<<<ogrid, 256, 0, stream>>>(CTXQb, WOb, bo, (float*)d_out);
}